// Round 4
// baseline (929.309 us; speedup 1.0000x reference)
//
#include <hip/hip_runtime.h>
#include <cstddef>

#define N_NODES 50000
#define N_EDGES 800000
#define N_PAIRS 100000

typedef float floatx4 __attribute__((ext_vector_type(4)));
typedef _Float16 half2v __attribute__((ext_vector_type(2)));
typedef _Float16 half4v __attribute__((ext_vector_type(4)));
typedef _Float16 half8v __attribute__((ext_vector_type(8)));

// packed MFMA A/B-fragment layout: [tile16][kchunk32][lane][8] (fp16)
__device__ inline size_t packA(int m, int k, int K) {
  return ((size_t)((m >> 4) * (K >> 5) + (k >> 5)) << 9) +
         ((((unsigned)k >> 3) & 3) << 7) + ((m & 15) << 3) + (k & 7);
}

// ---------------- weight prep (fold + transpose + pack, fp16)
__device__ inline float fold_val(int l, int r, int j, const float* Wk, const float* Wq,
                                 const float* Wv, const float* att, const float* msg,
                                 const float* pri) {
  if (j >= 128 && j < 256) return Wq[(l * 128 + r) * 128 + (j - 128)];
  int jj = j & 127, hh = jj >> 4, e = jj & 15;
  const float* W = (j < 128) ? Wk : Wv;
  const float* T = (j < 128) ? att : msg;
  float s = 0.f;
#pragma unroll
  for (int d = 0; d < 16; d++)
    s += W[(l * 128 + r) * 128 + hh * 16 + d] * T[((l * 8 + hh) * 16 + d) * 16 + e];
  if (j < 128) s *= pri[l * 8 + hh] * 0.25f;
  return s;
}

__global__ void wprep_kernel(const float* __restrict__ W_in, const float* __restrict__ Wk,
                             const float* __restrict__ Wq, const float* __restrict__ Wv,
                             const float* __restrict__ att, const float* __restrict__ msg,
                             const float* __restrict__ pri, const float* __restrict__ Wa,
                             const float* __restrict__ W1, const float* __restrict__ W2,
                             _Float16* Wint, _Float16* Wcat, _Float16* Waf,
                             _Float16* W1f, _Float16* W2f) {
  int gid = blockIdx.x * 256 + threadIdx.x;
  float v;
  _Float16* dt;
  size_t o;
  if (gid < 16384) {
    int n = gid >> 7, k = gid & 127;
    v = W_in[k * 128 + n];
    dt = Wint; o = packA(n, k, 128);
  } else if (gid < 163840) {
    int t = gid - 16384;
    int l = t / 49152, u = t - l * 49152;
    int n = u >> 7, k = u & 127;
    v = fold_val(l, k, n, Wk, Wq, Wv, att, msg, pri);
    dt = Wcat + (size_t)l * 49152;
    o = packA(n, k, 128);
  } else if (gid < 212992) {
    int t = gid - 163840;
    int l = t / 16384, u = t & 16383;
    int n = u >> 7, k = u & 127;
    v = Wa[(size_t)l * 16384 + k * 128 + n];
    dt = Waf + (size_t)l * 16384;
    o = packA(n, k, 128);
  } else if (gid < 221184) {
    int u = gid - 212992;
    int n = u >> 7, k = u & 127;
    v = W1[k * 64 + n];
    dt = W1f; o = packA(n, k, 128);
  } else if (gid < 225280) {
    int u = gid - 221184;
    int n = u >> 6, k = u & 63;
    v = (n < 32) ? W2[k * 32 + n] : 0.f;
    dt = W2f; o = packA(n, k, 64);
  } else {
    return;
  }
  dt[o] = (_Float16)v;
}

// ---------------- CSR build (padded to multiple of 4 per node)
__global__ void hist_kernel(const int* __restrict__ dst, int* __restrict__ deg, int E) {
  int g = blockIdx.x * blockDim.x + threadIdx.x;
  if (g < E) atomicAdd(&deg[dst[g]], 1);
}

__global__ void scanA_kernel(const int* __restrict__ deg, int* __restrict__ offs,
                             int* __restrict__ bsum, int n) {
  __shared__ int sm[256];
  int t = threadIdx.x;
  int i = blockIdx.x * 256 + t;
  // pad each node's slot count to a multiple of 4 (chunk granularity)
  int v = (i < n) ? ((deg[i] + 3) & ~3) : 0;
  sm[t] = v;
  __syncthreads();
  for (int off = 1; off < 256; off <<= 1) {
    int u = (t >= off) ? sm[t - off] : 0;
    __syncthreads();
    sm[t] += u;
    __syncthreads();
  }
  if (i < n) offs[i] = sm[t] - v;
  if (t == 255) bsum[blockIdx.x] = sm[255];
}

__global__ void scanB_kernel(const int* __restrict__ bsum, int* __restrict__ boff,
                             int* __restrict__ offs, int nb, int n) {
  __shared__ int sm[256];
  int t = threadIdx.x;
  int v = (t < nb) ? bsum[t] : 0;
  sm[t] = v;
  __syncthreads();
  for (int off = 1; off < 256; off <<= 1) {
    int u = (t >= off) ? sm[t - off] : 0;
    __syncthreads();
    sm[t] += u;
    __syncthreads();
  }
  boff[t] = sm[t] - v;
  if (t == nb - 1) offs[n] = sm[t];
}

__global__ void scanC_kernel(int* __restrict__ offs, const int* __restrict__ boff,
                             int* __restrict__ cursor, int n) {
  int i = blockIdx.x * 256 + threadIdx.x;
  if (i < n) {
    int o = offs[i] + boff[blockIdx.x];
    offs[i] = o;
    cursor[i] = o;
  }
}

__global__ void scatter_kernel(const int* __restrict__ src, const int* __restrict__ dst,
                               const float* __restrict__ w, int* __restrict__ cursor,
                               int2* __restrict__ eld, int E) {
  int g = blockIdx.x * blockDim.x + threadIdx.x;
  if (g < E) {
    int d = dst[g];
    int p = atomicAdd(&cursor[d], 1);
    eld[p] = make_int2(src[g], __float_as_int(w[g]));
  }
}

// ---------------- degree-descending node permutation (counting sort, 256 buckets)
__global__ void bhist_kernel(const int* __restrict__ deg, int* __restrict__ bh, int n) {
  __shared__ int lh[256];
  int t = threadIdx.x;
  lh[t] = 0;
  __syncthreads();
  int i = blockIdx.x * 256 + t;
  if (i < n) atomicAdd(&lh[min(deg[i], 255)], 1);
  __syncthreads();
  if (lh[t]) atomicAdd(&bh[t], lh[t]);
}
__global__ void bscan_kernel(const int* __restrict__ bh, int* __restrict__ bcur) {
  __shared__ int sm[256];
  int t = threadIdx.x;
  int v = bh[255 - t];
  sm[t] = v;
  __syncthreads();
  for (int off = 1; off < 256; off <<= 1) {
    int u = (t >= off) ? sm[t - off] : 0;
    __syncthreads();
    sm[t] += u;
    __syncthreads();
  }
  bcur[255 - t] = sm[t] - v;
}
__global__ void bscatter_kernel(const int* __restrict__ deg, int* __restrict__ bcur,
                                int* __restrict__ perm, int n) {
  __shared__ int lh[256], lbase[256];
  int t = threadIdx.x;
  lh[t] = 0;
  __syncthreads();
  int i = blockIdx.x * 256 + t;
  int b = 0, local = 0;
  if (i < n) {
    b = min(deg[i], 255);
    local = atomicAdd(&lh[b], 1);
  }
  __syncthreads();
  int cnt = lh[t];
  lbase[t] = cnt ? atomicAdd(&bcur[t], cnt) : 0;
  __syncthreads();
  if (i < n) perm[lbase[b] + local] = i;
}

// ---------------- fused layer kernel: GEMM1 (h) -> LDS fragments -> GEMM2 (kqv)
template <int FIRST>
__global__ __launch_bounds__(256) void fused_layer(
    const float* __restrict__ x, const _Float16* __restrict__ aggp,
    const _Float16* __restrict__ Wg1, const float* __restrict__ bias,
    const float* __restrict__ skipv, _Float16* __restrict__ hbuf,
    const _Float16* __restrict__ Wcat_l,
    _Float16* __restrict__ kwmv, _Float16* __restrict__ qbuf, int M) {
  int tid = threadIdx.x;
  int wave = tid >> 6, lane = tid & 63;
  int l16 = lane & 15, q = lane >> 4;
  int g = q, mloc = l16;
  int tile = blockIdx.x * 4 + wave;
  int m0 = tile * 16;
  bool alive = m0 < M;
  int tileC = alive ? tile : 0;

  __shared__ _Float16 htile_s[4][2048];
  __shared__ float ldsT_s[4][16 * 68];
  _Float16* htile = htile_s[wave];
  float* myT = ldsT_s[wave];

  // GEMM1 A fragments
  half8v a[4];
#pragma unroll
  for (int kc = 0; kc < 4; kc++) {
    if (FIRST) {
      int row = min(m0 + l16, M - 1);
      const float* p = x + (size_t)row * 128 + kc * 32 + q * 8;
      float4 u0 = *(const float4*)p, u1 = *(const float4*)(p + 4);
      float f[8] = {u0.x, u0.y, u0.z, u0.w, u1.x, u1.y, u1.z, u1.w};
      half8v hv;
#pragma unroll
      for (int i = 0; i < 8; i++) hv[i] = (_Float16)f[i];
      a[kc] = hv;
    } else {
      a[kc] = *(const half8v*)(aggp + (size_t)tileC * 2048 + (kc << 9) + lane * 8);
    }
  }

  float alpha = 1.f, beta = 0.f;
  if (!FIRST) {
    float sv = *skipv;
    alpha = 1.f / (1.f + __expf(-sv));
    beta = 1.f - alpha;
  }

  floatx4 acc1[8];
#pragma unroll
  for (int nt = 0; nt < 8; nt++) acc1[nt] = (floatx4){0.f, 0.f, 0.f, 0.f};
#pragma unroll
  for (int kc = 0; kc < 4; kc++) {
    half8v b[8];
#pragma unroll
    for (int nt = 0; nt < 8; nt++)
      b[nt] = *(const half8v*)(Wg1 + (size_t)nt * 2048 + (kc << 9) + lane * 8);
#pragma unroll
    for (int nt = 0; nt < 8; nt++)
      acc1[nt] = __builtin_amdgcn_mfma_f32_16x16x32_f16(a[kc], b[nt], acc1[nt], 0, 0, 0);
  }

  // epilogue1: per-64-col transpose; emit packed hbuf + LDS h-tile fragments
#pragma unroll
  for (int p = 0; p < 2; p++) {
    __syncthreads();
#pragma unroll
    for (int ntl = 0; ntl < 4; ntl++)
#pragma unroll
      for (int r = 0; r < 4; r++)
        myT[(q * 4 + r) * 68 + ntl * 16 + l16] = acc1[p * 4 + ntl][r];
    __syncthreads();
#pragma unroll
    for (int kc2 = 0; kc2 < 2; kc2++) {
      const float* rp = myT + mloc * 68 + kc2 * 32 + g * 8;
      floatx4 v0 = *(const floatx4*)rp;
      floatx4 v1 = *(const floatx4*)(rp + 4);
      float vals[8] = {v0[0], v0[1], v0[2], v0[3], v1[0], v1[1], v1[2], v1[3]};
      int col0 = p * 64 + kc2 * 32 + g * 8;
      size_t pbaseL = ((size_t)(tileC * 4 + (col0 >> 5)) << 9) + (size_t)lane * 8;
      if (FIRST) {
        float4 bb0 = *(const float4*)&bias[col0];
        float4 bb1 = *(const float4*)&bias[col0 + 4];
        float bbv[8] = {bb0.x, bb0.y, bb0.z, bb0.w, bb1.x, bb1.y, bb1.z, bb1.w};
#pragma unroll
        for (int j = 0; j < 8; j++) vals[j] = fmaxf(vals[j] + bbv[j], 0.f);
      } else {
        half8v hv = *(const half8v*)(hbuf + pbaseL);
#pragma unroll
        for (int j = 0; j < 8; j++)
          vals[j] = fmaxf(alpha * vals[j] + beta * (float)hv[j], 0.f);
      }
      half8v h8;
#pragma unroll
      for (int j = 0; j < 8; j++) h8[j] = (_Float16)vals[j];
      *(half8v*)(htile + (((p * 2 + kc2) << 9) + (g << 7) + (mloc << 3))) = h8;
      if (alive) *(half8v*)(hbuf + pbaseL) = h8;
    }
  }

  // GEMM2: kqv = h-tile @ Wcat (384 cols, 6 chunks of 64)
  for (int c = 0; c < 6; c++) {
    floatx4 acc2[4];
#pragma unroll
    for (int nt = 0; nt < 4; nt++) acc2[nt] = (floatx4){0.f, 0.f, 0.f, 0.f};
#pragma unroll
    for (int kc = 0; kc < 4; kc++) {
      half8v af = *(const half8v*)(htile + ((kc << 9) + lane * 8));
      half8v b[4];
#pragma unroll
      for (int nt = 0; nt < 4; nt++)
        b[nt] = *(const half8v*)(Wcat_l + (size_t)(c * 4 + nt) * 2048 + (kc << 9) + lane * 8);
#pragma unroll
      for (int nt = 0; nt < 4; nt++)
        acc2[nt] = __builtin_amdgcn_mfma_f32_16x16x32_f16(af, b[nt], acc2[nt], 0, 0, 0);
    }
    __syncthreads();
#pragma unroll
    for (int ntl = 0; ntl < 4; ntl++)
#pragma unroll
      for (int r = 0; r < 4; r++)
        myT[(q * 4 + r) * 68 + ntl * 16 + l16] = acc2[ntl][r];
    __syncthreads();
    if (alive) {
      int row = m0 + mloc;
#pragma unroll
      for (int kc2 = 0; kc2 < 2; kc2++) {
        const float* rp = myT + mloc * 68 + kc2 * 32 + g * 8;
        floatx4 v0 = *(const floatx4*)rp;
        floatx4 v1 = *(const floatx4*)(rp + 4);
        int col0 = c * 64 + kc2 * 32 + g * 8;
        int region = col0 >> 7;  // 0 kw, 1 q, 2 mv
        if (region == 1) {
          half8v h8;
#pragma unroll
          for (int j = 0; j < 4; j++) {
            h8[j] = (_Float16)v0[j];
            h8[j + 4] = (_Float16)v1[j];
          }
          *(half8v*)&qbuf[(size_t)row * 128 + (col0 - 128)] = h8;
        } else {
          int cc = col0 & 127;
          size_t base = (size_t)row * 256 + (size_t)(cc >> 2) * 8 + (region == 2 ? 4 : 0);
          half4v h0, h1;
#pragma unroll
          for (int j = 0; j < 4; j++) {
            h0[j] = (_Float16)v0[j];
            h1[j] = (_Float16)v1[j];
          }
          *(half4v*)&kwmv[base] = h0;
          *(half4v*)&kwmv[base + 8] = h1;
        }
      }
    }
  }
}

// ---------------- last Wa GEMM: hfinal = mix(agg @ Wa2, hold) (no relu) + hrow fp16
__global__ __launch_bounds__(256) void gemm_last(
    const _Float16* __restrict__ aggp, const _Float16* __restrict__ Wg1,
    const float* __restrict__ skipv, const _Float16* __restrict__ hbuf,
    float* __restrict__ hfinal, _Float16* __restrict__ hrow, int M) {
  int tid = threadIdx.x;
  int wave = tid >> 6, lane = tid & 63;
  int l16 = lane & 15, q = lane >> 4;
  int g = q, mloc = l16;
  int tile = blockIdx.x * 4 + wave;
  int m0 = tile * 16;
  bool alive = m0 < M;
  int tileC = alive ? tile : 0;

  __shared__ float ldsT_s[4][16 * 68];
  float* myT = ldsT_s[wave];

  half8v a[4];
#pragma unroll
  for (int kc = 0; kc < 4; kc++)
    a[kc] = *(const half8v*)(aggp + (size_t)tileC * 2048 + (kc << 9) + lane * 8);

  float sv = *skipv;
  float alpha = 1.f / (1.f + __expf(-sv));
  float beta = 1.f - alpha;

  floatx4 acc1[8];
#pragma unroll
  for (int nt = 0; nt < 8; nt++) acc1[nt] = (floatx4){0.f, 0.f, 0.f, 0.f};
#pragma unroll
  for (int kc = 0; kc < 4; kc++) {
    half8v b[8];
#pragma unroll
    for (int nt = 0; nt < 8; nt++)
      b[nt] = *(const half8v*)(Wg1 + (size_t)nt * 2048 + (kc << 9) + lane * 8);
#pragma unroll
    for (int nt = 0; nt < 8; nt++)
      acc1[nt] = __builtin_amdgcn_mfma_f32_16x16x32_f16(a[kc], b[nt], acc1[nt], 0, 0, 0);
  }

#pragma unroll
  for (int p = 0; p < 2; p++) {
    __syncthreads();
#pragma unroll
    for (int ntl = 0; ntl < 4; ntl++)
#pragma unroll
      for (int r = 0; r < 4; r++)
        myT[(q * 4 + r) * 68 + ntl * 16 + l16] = acc1[p * 4 + ntl][r];
    __syncthreads();
    if (alive) {
      int row = m0 + mloc;
#pragma unroll
      for (int kc2 = 0; kc2 < 2; kc2++) {
        const float* rp = myT + mloc * 68 + kc2 * 32 + g * 8;
        floatx4 v0 = *(const floatx4*)rp;
        floatx4 v1 = *(const floatx4*)(rp + 4);
        float vals[8] = {v0[0], v0[1], v0[2], v0[3], v1[0], v1[1], v1[2], v1[3]};
        int col0 = p * 64 + kc2 * 32 + g * 8;
        size_t pbase = ((size_t)(tile * 4 + (col0 >> 5)) << 9) + (size_t)lane * 8;
        half8v hv = *(const half8v*)(hbuf + pbase);
#pragma unroll
        for (int j = 0; j < 8; j++) vals[j] = alpha * vals[j] + beta * (float)hv[j];
        *(float4*)&hfinal[(size_t)row * 128 + col0] =
            make_float4(vals[0], vals[1], vals[2], vals[3]);
        *(float4*)&hfinal[(size_t)row * 128 + col0 + 4] =
            make_float4(vals[4], vals[5], vals[6], vals[7]);
        half8v h8;
#pragma unroll
        for (int j = 0; j < 8; j++) h8[j] = (_Float16)vals[j];
        *(half8v*)&hrow[(size_t)row * 128 + col0] = h8;
      }
    }
  }
}

// ---------------- fused predictor: Z=h[a]*h[b] -> W1+leaky -> W2+leaky -> dot W3
__global__ __launch_bounds__(256) void pred_fused(
    const _Float16* __restrict__ hrow,
    const int* __restrict__ ps, const int* __restrict__ pd,
    const int* __restrict__ ns, const int* __restrict__ nd,
    const _Float16* __restrict__ W1f, const float* __restrict__ b1,
    const _Float16* __restrict__ W2f, const float* __restrict__ b2,
    const float* __restrict__ W3, const float* __restrict__ b3,
    float* __restrict__ outd, int M) {
  int tid = threadIdx.x;
  int wave = tid >> 6, lane = tid & 63;
  int l16 = lane & 15, q = lane >> 4;
  int g = q, mloc = l16;
  int tile = blockIdx.x * 4 + wave;
  int m0 = tile * 16;
  bool alive = m0 < M;

  __shared__ _Float16 t1_s[4][1024];
  __shared__ float ldsT_s[4][16 * 68];
  _Float16* t1tile = t1_s[wave];
  float* myT = ldsT_s[wave];

  int gr = min(m0 + l16, M - 1);
  bool pos = gr < N_PAIRS;
  int idx = pos ? gr : gr - N_PAIRS;
  int pa = pos ? ps[idx] : ns[idx];
  int pb = pos ? pd[idx] : nd[idx];

  half8v a[4];
#pragma unroll
  for (int kc = 0; kc < 4; kc++) {
    int kbase = kc * 32 + q * 8;
    half8v ha = *(const half8v*)(hrow + (size_t)pa * 128 + kbase);
    half8v hb = *(const half8v*)(hrow + (size_t)pb * 128 + kbase);
    a[kc] = ha * hb;
  }

  floatx4 acc1[4];
#pragma unroll
  for (int nt = 0; nt < 4; nt++) acc1[nt] = (floatx4){0.f, 0.f, 0.f, 0.f};
#pragma unroll
  for (int kc = 0; kc < 4; kc++) {
    half8v b[4];
#pragma unroll
    for (int nt = 0; nt < 4; nt++)
      b[nt] = *(const half8v*)(W1f + (size_t)nt * 2048 + (kc << 9) + lane * 8);
#pragma unroll
    for (int nt = 0; nt < 4; nt++)
      acc1[nt] = __builtin_amdgcn_mfma_f32_16x16x32_f16(a[kc], b[nt], acc1[nt], 0, 0, 0);
  }

  // epilogue1: bias+leaky -> per-wave T1 fragments (16 rows x 64 k)
  __syncthreads();
#pragma unroll
  for (int ntl = 0; ntl < 4; ntl++)
#pragma unroll
    for (int r = 0; r < 4; r++)
      myT[(q * 4 + r) * 68 + ntl * 16 + l16] = acc1[ntl][r];
  __syncthreads();
#pragma unroll
  for (int kc2 = 0; kc2 < 2; kc2++) {
    const float* rp = myT + mloc * 68 + kc2 * 32 + g * 8;
    floatx4 v0 = *(const floatx4*)rp;
    floatx4 v1 = *(const floatx4*)(rp + 4);
    float vals[8] = {v0[0], v0[1], v0[2], v0[3], v1[0], v1[1], v1[2], v1[3]};
    int col0 = kc2 * 32 + g * 8;
    float4 bb0 = *(const float4*)&b1[col0];
    float4 bb1 = *(const float4*)&b1[col0 + 4];
    float bbv[8] = {bb0.x, bb0.y, bb0.z, bb0.w, bb1.x, bb1.y, bb1.z, bb1.w};
    half8v h8;
#pragma unroll
    for (int j = 0; j < 8; j++) {
      float v = vals[j] + bbv[j];
      v = v > 0.f ? v : 0.2f * v;
      h8[j] = (_Float16)v;
    }
    *(half8v*)(t1tile + ((kc2 << 9) + (g << 7) + (mloc << 3))) = h8;
  }

  // GEMM2: T1 @ W2 (K=64, N=32) + leaky + dot W3
  floatx4 acc2[2];
#pragma unroll
  for (int nt = 0; nt < 2; nt++) acc2[nt] = (floatx4){0.f, 0.f, 0.f, 0.f};
#pragma unroll
  for (int kc = 0; kc < 2; kc++) {
    half8v af = *(const half8v*)(t1tile + ((kc << 9) + lane * 8));
    half8v b[2];
#pragma unroll
    for (int nt = 0; nt < 2; nt++)
      b[nt] = *(const half8v*)(W2f + (size_t)nt * 1024 + (kc << 9) + lane * 8);
#pragma unroll
    for (int nt = 0; nt < 2; nt++)
      acc2[nt] = __builtin_amdgcn_mfma_f32_16x16x32_f16(af, b[nt], acc2[nt], 0, 0, 0);
  }

  float bw[2], wv[2];
#pragma unroll
  for (int nt = 0; nt < 2; nt++) {
    int col = nt * 16 + l16;
    bw[nt] = b2[col];
    wv[nt] = W3[col];
  }
  float b3v = b3[0];
#pragma unroll
  for (int r = 0; r < 4; r++) {
    float partial = 0.f;
#pragma unroll
    for (int nt = 0; nt < 2; nt++) {
      float v = acc2[nt][r] + bw[nt];
      v = v > 0.f ? v : 0.2f * v;
      partial += v * wv[nt];
    }
    partial += __shfl_xor(partial, 1);
    partial += __shfl_xor(partial, 2);
    partial += __shfl_xor(partial, 4);
    partial += __shfl_xor(partial, 8);
    int row = m0 + q * 4 + r;
    if (l16 == 0 && alive && row < M) outd[row] = partial + b3v;
  }
}

// ---------------- per-destination online-softmax aggregation
// one node per HALF-wave; chunk=4 edges, depth-2 ping-pong gather pipeline.
// sentinel detection is INDEX-based (slot >= beg+deg) so src registers die at
// issue time -> fits <=64 VGPR -> 8 waves/SIMD (launch_bounds enforced).
#define LOAD4(J, S)                                                       \
  _Pragma("unroll") for (int i = 0; i < 4; i++) S[i] = esrc[((J) + i) * 2];

#define ISSUE4(S, G)                                                      \
  _Pragma("unroll") for (int i = 0; i < 4; i++)                           \
      G[i] = *(const half8v*)&kwmv[(size_t)max(S[i], 0) * 256 + lofs];

#define COMPUTE4(J, G)                                                    \
  {                                                                       \
    float p[4];                                                           \
    _Pragma("unroll") for (int i = 0; i < 4; i++) {                       \
      half2v k01 = {G[i][0], G[i][1]}, k23 = {G[i][2], G[i][3]};          \
      float d = __builtin_amdgcn_fdot2(                                   \
          k01, q01, __builtin_amdgcn_fdot2(k23, q23, 0.f, false), false); \
      d += __shfl_xor(d, 1);                                              \
      d += __shfl_xor(d, 2);                                              \
      p[i] = ((J) + i < dend) ? d : -1e30f;                               \
    }                                                                     \
    float nm = m;                                                         \
    _Pragma("unroll") for (int i = 0; i < 4; i++) nm = fmaxf(nm, p[i]);   \
    float sc = __expf(m - nm);                                            \
    float t[4], ssum = 0.f;                                               \
    _Pragma("unroll") for (int i = 0; i < 4; i++) {                       \
      t[i] = __expf(p[i] - nm);                                           \
      ssum += t[i];                                                       \
    }                                                                     \
    s = s * sc + ssum;                                                    \
    a0 *= sc; a1 *= sc; a2 *= sc; a3 *= sc;                               \
    _Pragma("unroll") for (int i = 0; i < 4; i++) {                       \
      float w = ((J) + i < dend)                                          \
                    ? __int_as_float(esrc[((J) + i) * 2 + 1]) : 0.f;      \
      float f = t[i] * w;                                                 \
      a0 += f * (float)G[i][4];                                           \
      a1 += f * (float)G[i][5];                                           \
      a2 += f * (float)G[i][6];                                           \
      a3 += f * (float)G[i][7];                                           \
    }                                                                     \
    m = nm;                                                               \
  }

__global__ __launch_bounds__(256, 8) void edge_agg_kernel(
    const _Float16* __restrict__ kwmv, const _Float16* __restrict__ qbuf,
    const int* __restrict__ poffs, const int2* __restrict__ eld,
    const int* __restrict__ perm, const int* __restrict__ deg,
    _Float16* __restrict__ agg, int n) {
  int hw = (blockIdx.x * 256 + threadIdx.x) >> 5;  // half-wave stream id
  int stride = gridDim.x << 3;                     // half-waves in grid
  int c4 = threadIdx.x & 31;
  int ch = c4 << 2;
  size_t lofs = (size_t)c4 * 8;
  const int* esrc = (const int*)eld;  // slot i -> {src at 2i, wbits at 2i+1}
  for (int gw = hw; gw < n; gw += stride) {
    int node = perm[gw];
    half4v qv = *(const half4v*)&qbuf[(size_t)node * 128 + ch];
    half2v q01 = {qv[0], qv[1]}, q23 = {qv[2], qv[3]};
    float m = -1e30f, s = 0.f;
    float a0 = 0.f, a1 = 0.f, a2 = 0.f, a3 = 0.f;
    int beg = poffs[node], end = poffs[node + 1];
    int dend = beg + deg[node];
    if (beg < end) {
      int sA[4], sB[4];
      half8v gA[4], gB[4];
      // prologue: issue chunks 0 and 1 (chunk1 may be past end -> harmless read)
      LOAD4(beg, sA);
      ISSUE4(sA, gA);
      LOAD4(beg + 4, sB);
      ISSUE4(sB, gB);
      __builtin_amdgcn_sched_barrier(0);
      int j = beg;
      for (; j + 8 < end; j += 8) {
        // metas for chunks j+8, j+12 (may overrun: sentinel pad region)
        LOAD4(j + 8, sA);
        LOAD4(j + 12, sB);
        COMPUTE4(j, gA);
        ISSUE4(sA, gA);  // refill A with chunk j+8
        __builtin_amdgcn_sched_barrier(0);
        COMPUTE4(j + 4, gB);
        ISSUE4(sB, gB);  // refill B with chunk j+12
        __builtin_amdgcn_sched_barrier(0);
      }
      COMPUTE4(j, gA);
      if (j + 4 < end) COMPUTE4(j + 4, gB);
    }
    float inv = (s > 0.f) ? 1.f / s : 0.f;
    half4v out4;
    out4[0] = (_Float16)(a0 * inv);
    out4[1] = (_Float16)(a1 * inv);
    out4[2] = (_Float16)(a2 * inv);
    out4[3] = (_Float16)(a3 * inv);
    *(half4v*)&agg[packA(node, ch, 128)] = out4;
  }
}

extern "C" void kernel_launch(void* const* d_in, const int* in_sizes, int n_in,
                              void* d_out, int out_size, void* d_ws, size_t ws_size,
                              hipStream_t stream) {
  const float* x        = (const float*)d_in[0];
  const int*   edge_src = (const int*)d_in[1];
  const int*   edge_dst = (const int*)d_in[2];
  const float* edge_w   = (const float*)d_in[3];
  const int*   pos_src  = (const int*)d_in[4];
  const int*   pos_dst  = (const int*)d_in[5];
  const int*   neg_src  = (const int*)d_in[6];
  const int*   neg_dst  = (const int*)d_in[7];
  const float* W_in     = (const float*)d_in[8];
  const float* b_in     = (const float*)d_in[9];
  const float* Wk       = (const float*)d_in[10];
  const float* Wq       = (const float*)d_in[11];
  const float* Wv       = (const float*)d_in[12];
  const float* att_w    = (const float*)d_in[13];
  const float* msg_w    = (const float*)d_in[14];
  const float* pri      = (const float*)d_in[15];
  const float* Wa       = (const float*)d_in[16];
  const float* skip     = (const float*)d_in[17];
  const float* W1       = (const float*)d_in[18];
  const float* b1       = (const float*)d_in[19];
  const float* W2       = (const float*)d_in[20];
  const float* b2       = (const float*)d_in[21];
  const float* W3       = (const float*)d_in[22];
  const float* b3       = (const float*)d_in[23];
  float* out = (float*)d_out;

  // ---- workspace layout (bytes), ~91 MB
  char* W = (char*)d_ws;
  _Float16*  qbuf   = (_Float16*)(W + 0);          // 12,800,000
  _Float16*  kwmv   = (_Float16*)(W + 12800000);   // 25,600,000
  _Float16*  hbuf   = (_Float16*)(W + 38400000);   // 12,800,000 (packed h)
  _Float16*  agg    = (_Float16*)(W + 51200000);   // 12,800,000
  _Float16*  Wint   = (_Float16*)(W + 64000000);   // 32,768
  _Float16*  Wcat   = (_Float16*)(W + 64032768);   // 294,912
  _Float16*  Waf    = (_Float16*)(W + 64327680);   // 98,304
  _Float16*  W1f    = (_Float16*)(W + 64425984);   // 16,384
  _Float16*  W2f    = (_Float16*)(W + 64442368);   // 8,192
  int2*      eld    = (int2*)(W + 64450560);       // 12,800,000 (padded-4 edges)
  int*       deg    = (int*)(W + 77250560);        // 200,000
  int*       poffs  = (int*)(W + 77450560);        // 200,016
  int*       cursor = (int*)(W + 77650576);        // 200,000
  int*       perm   = (int*)(W + 77850576);        // 200,000
  int*       bsum   = (int*)(W + 78050576);        // 1,024
  int*       boff   = (int*)(W + 78051600);        // 1,024
  int*       bh     = (int*)(W + 78052624);        // 1,024
  int*       bcur   = (int*)(W + 78053648);        // 1,024
  _Float16*  hrow   = (_Float16*)(W + 78054912);   // 12,800,000 (fp16 row-major hfinal)
  float* hfinal = out + 2 * N_PAIRS;

  hipMemsetAsync(deg, 0, N_NODES * sizeof(int), stream);
  hipMemsetAsync(bh, 0, 1024, stream);
  // sentinel: src=-1. pad-4 worst case: E + 3*N slots = 7.6MB (+prefetch overrun)
  hipMemsetAsync(eld, 0xFF, 8000000, stream);

  wprep_kernel<<<880, 256, 0, stream>>>(W_in, Wk, Wq, Wv, att_w, msg_w, pri, Wa, W1, W2,
                                        Wint, Wcat, Waf, W1f, W2f);
  hist_kernel<<<(N_EDGES + 255) / 256, 256, 0, stream>>>(edge_dst, deg, N_EDGES);
  scanA_kernel<<<196, 256, 0, stream>>>(deg, poffs, bsum, N_NODES);
  scanB_kernel<<<1, 256, 0, stream>>>(bsum, boff, poffs, 196, N_NODES);
  scanC_kernel<<<196, 256, 0, stream>>>(poffs, boff, cursor, N_NODES);
  scatter_kernel<<<(N_EDGES + 255) / 256, 256, 0, stream>>>(
      edge_src, edge_dst, edge_w, cursor, eld, N_EDGES);
  bhist_kernel<<<196, 256, 0, stream>>>(deg, bh, N_NODES);
  bscan_kernel<<<1, 256, 0, stream>>>(bh, bcur);
  bscatter_kernel<<<196, 256, 0, stream>>>(deg, bcur, perm, N_NODES);

  // layer 0: x -> h_in (relu proj) -> kqv0
  fused_layer<1><<<782, 256, 0, stream>>>(x, nullptr, Wint, b_in, nullptr, hbuf,
                                          Wcat, kwmv, qbuf, N_NODES);
  edge_agg_kernel<<<2048, 256, 0, stream>>>(kwmv, qbuf, poffs, eld, perm, deg,
                                            agg, N_NODES);
  // layer 1: agg0 -> h0 (skip-mix+relu) -> kqv1
  fused_layer<0><<<782, 256, 0, stream>>>(nullptr, agg, Waf, nullptr, skip + 0, hbuf,
                                          Wcat + 49152, kwmv, qbuf, N_NODES);
  edge_agg_kernel<<<2048, 256, 0, stream>>>(kwmv, qbuf, poffs, eld, perm, deg,
                                            agg, N_NODES);
  // layer 2: agg1 -> h1 (skip-mix+relu) -> kqv2
  fused_layer<0><<<782, 256, 0, stream>>>(nullptr, agg, Waf + 16384, nullptr, skip + 1,
                                          hbuf, Wcat + 98304, kwmv, qbuf, N_NODES);
  edge_agg_kernel<<<2048, 256, 0, stream>>>(kwmv, qbuf, poffs, eld, perm, deg,
                                            agg, N_NODES);
  // final: agg2 -> hfinal (skip-mix, no relu) + hrow fp16
  gemm_last<<<782, 256, 0, stream>>>(agg, Waf + 32768, skip + 2, hbuf,
                                     hfinal, hrow, N_NODES);
  // predictor (fully fused)
  pred_fused<<<3125, 256, 0, stream>>>(hrow, pos_src, pos_dst, neg_src, neg_dst,
                                       W1f, b1, W2f, b2, W3, b3, out, 2 * N_PAIRS);
}

// Round 5
// 561.459 us; speedup vs baseline: 1.6552x; 1.6552x over previous
//
#include <hip/hip_runtime.h>
#include <cstddef>

#pragma clang diagnostic ignored "-Waddress-space-conversion"

#define N_NODES 50000
#define N_EDGES 800000
#define N_PAIRS 100000

typedef float floatx4 __attribute__((ext_vector_type(4)));
typedef _Float16 half2v __attribute__((ext_vector_type(2)));
typedef _Float16 half4v __attribute__((ext_vector_type(4)));
typedef _Float16 half8v __attribute__((ext_vector_type(8)));

// packed MFMA A/B-fragment layout: [tile16][kchunk32][lane][8] (fp16)
__device__ inline size_t packA(int m, int k, int K) {
  return ((size_t)((m >> 4) * (K >> 5) + (k >> 5)) << 9) +
         ((((unsigned)k >> 3) & 3) << 7) + ((m & 15) << 3) + (k & 7);
}

// ---------------- weight prep (fold + transpose + pack, fp16)
__device__ inline float fold_val(int l, int r, int j, const float* Wk, const float* Wq,
                                 const float* Wv, const float* att, const float* msg,
                                 const float* pri) {
  if (j >= 128 && j < 256) return Wq[(l * 128 + r) * 128 + (j - 128)];
  int jj = j & 127, hh = jj >> 4, e = jj & 15;
  const float* W = (j < 128) ? Wk : Wv;
  const float* T = (j < 128) ? att : msg;
  float s = 0.f;
#pragma unroll
  for (int d = 0; d < 16; d++)
    s += W[(l * 128 + r) * 128 + hh * 16 + d] * T[((l * 8 + hh) * 16 + d) * 16 + e];
  if (j < 128) s *= pri[l * 8 + hh] * 0.25f;
  return s;
}

__global__ void wprep_kernel(const float* __restrict__ W_in, const float* __restrict__ Wk,
                             const float* __restrict__ Wq, const float* __restrict__ Wv,
                             const float* __restrict__ att, const float* __restrict__ msg,
                             const float* __restrict__ pri, const float* __restrict__ Wa,
                             const float* __restrict__ W1, const float* __restrict__ W2,
                             _Float16* Wint, _Float16* Wcat, _Float16* Waf,
                             _Float16* W1f, _Float16* W2f) {
  int gid = blockIdx.x * 256 + threadIdx.x;
  float v;
  _Float16* dt;
  size_t o;
  if (gid < 16384) {
    int n = gid >> 7, k = gid & 127;
    v = W_in[k * 128 + n];
    dt = Wint; o = packA(n, k, 128);
  } else if (gid < 163840) {
    int t = gid - 16384;
    int l = t / 49152, u = t - l * 49152;
    int n = u >> 7, k = u & 127;
    v = fold_val(l, k, n, Wk, Wq, Wv, att, msg, pri);
    dt = Wcat + (size_t)l * 49152;
    o = packA(n, k, 128);
  } else if (gid < 212992) {
    int t = gid - 163840;
    int l = t / 16384, u = t & 16383;
    int n = u >> 7, k = u & 127;
    v = Wa[(size_t)l * 16384 + k * 128 + n];
    dt = Waf + (size_t)l * 16384;
    o = packA(n, k, 128);
  } else if (gid < 221184) {
    int u = gid - 212992;
    int n = u >> 7, k = u & 127;
    v = W1[k * 64 + n];
    dt = W1f; o = packA(n, k, 128);
  } else if (gid < 225280) {
    int u = gid - 221184;
    int n = u >> 6, k = u & 63;
    v = (n < 32) ? W2[k * 32 + n] : 0.f;
    dt = W2f; o = packA(n, k, 64);
  } else {
    return;
  }
  dt[o] = (_Float16)v;
}

// ---------------- CSR build (padded to multiple of 4 per node)
__global__ void hist_kernel(const int* __restrict__ dst, int* __restrict__ deg, int E) {
  int g = blockIdx.x * blockDim.x + threadIdx.x;
  if (g < E) atomicAdd(&deg[dst[g]], 1);
}

__global__ void scanA_kernel(const int* __restrict__ deg, int* __restrict__ offs,
                             int* __restrict__ bsum, int n) {
  __shared__ int sm[256];
  int t = threadIdx.x;
  int i = blockIdx.x * 256 + t;
  // pad each node's slot count to a multiple of 4 (chunk granularity)
  int v = (i < n) ? ((deg[i] + 3) & ~3) : 0;
  sm[t] = v;
  __syncthreads();
  for (int off = 1; off < 256; off <<= 1) {
    int u = (t >= off) ? sm[t - off] : 0;
    __syncthreads();
    sm[t] += u;
    __syncthreads();
  }
  if (i < n) offs[i] = sm[t] - v;
  if (t == 255) bsum[blockIdx.x] = sm[255];
}

__global__ void scanB_kernel(const int* __restrict__ bsum, int* __restrict__ boff,
                             int* __restrict__ offs, int nb, int n) {
  __shared__ int sm[256];
  int t = threadIdx.x;
  int v = (t < nb) ? bsum[t] : 0;
  sm[t] = v;
  __syncthreads();
  for (int off = 1; off < 256; off <<= 1) {
    int u = (t >= off) ? sm[t - off] : 0;
    __syncthreads();
    sm[t] += u;
    __syncthreads();
  }
  boff[t] = sm[t] - v;
  if (t == nb - 1) offs[n] = sm[t];
}

__global__ void scanC_kernel(int* __restrict__ offs, const int* __restrict__ boff,
                             int* __restrict__ cursor, int n) {
  int i = blockIdx.x * 256 + threadIdx.x;
  if (i < n) {
    int o = offs[i] + boff[blockIdx.x];
    offs[i] = o;
    cursor[i] = o;
  }
}

__global__ void scatter_kernel(const int* __restrict__ src, const int* __restrict__ dst,
                               const float* __restrict__ w, int* __restrict__ cursor,
                               int2* __restrict__ eld, int E) {
  int g = blockIdx.x * blockDim.x + threadIdx.x;
  if (g < E) {
    int d = dst[g];
    int p = atomicAdd(&cursor[d], 1);
    eld[p] = make_int2(src[g], __float_as_int(w[g]));
  }
}

// ---------------- degree-descending node permutation (counting sort, 256 buckets)
__global__ void bhist_kernel(const int* __restrict__ deg, int* __restrict__ bh, int n) {
  __shared__ int lh[256];
  int t = threadIdx.x;
  lh[t] = 0;
  __syncthreads();
  int i = blockIdx.x * 256 + t;
  if (i < n) atomicAdd(&lh[min(deg[i], 255)], 1);
  __syncthreads();
  if (lh[t]) atomicAdd(&bh[t], lh[t]);
}
__global__ void bscan_kernel(const int* __restrict__ bh, int* __restrict__ bcur) {
  __shared__ int sm[256];
  int t = threadIdx.x;
  int v = bh[255 - t];
  sm[t] = v;
  __syncthreads();
  for (int off = 1; off < 256; off <<= 1) {
    int u = (t >= off) ? sm[t - off] : 0;
    __syncthreads();
    sm[t] += u;
    __syncthreads();
  }
  bcur[255 - t] = sm[t] - v;
}
__global__ void bscatter_kernel(const int* __restrict__ deg, int* __restrict__ bcur,
                                int* __restrict__ perm, int n) {
  __shared__ int lh[256], lbase[256];
  int t = threadIdx.x;
  lh[t] = 0;
  __syncthreads();
  int i = blockIdx.x * 256 + t;
  int b = 0, local = 0;
  if (i < n) {
    b = min(deg[i], 255);
    local = atomicAdd(&lh[b], 1);
  }
  __syncthreads();
  int cnt = lh[t];
  lbase[t] = cnt ? atomicAdd(&bcur[t], cnt) : 0;
  __syncthreads();
  if (i < n) perm[lbase[b] + local] = i;
}

// ---------------- fused layer kernel: GEMM1 (h) -> LDS fragments -> GEMM2 (kqv)
template <int FIRST>
__global__ __launch_bounds__(256) void fused_layer(
    const float* __restrict__ x, const _Float16* __restrict__ aggp,
    const _Float16* __restrict__ Wg1, const float* __restrict__ bias,
    const float* __restrict__ skipv, _Float16* __restrict__ hbuf,
    const _Float16* __restrict__ Wcat_l,
    _Float16* __restrict__ kwmv, _Float16* __restrict__ qbuf, int M) {
  int tid = threadIdx.x;
  int wave = tid >> 6, lane = tid & 63;
  int l16 = lane & 15, q = lane >> 4;
  int g = q, mloc = l16;
  int tile = blockIdx.x * 4 + wave;
  int m0 = tile * 16;
  bool alive = m0 < M;
  int tileC = alive ? tile : 0;

  __shared__ _Float16 htile_s[4][2048];
  __shared__ float ldsT_s[4][16 * 68];
  _Float16* htile = htile_s[wave];
  float* myT = ldsT_s[wave];

  // GEMM1 A fragments
  half8v a[4];
#pragma unroll
  for (int kc = 0; kc < 4; kc++) {
    if (FIRST) {
      int row = min(m0 + l16, M - 1);
      const float* p = x + (size_t)row * 128 + kc * 32 + q * 8;
      float4 u0 = *(const float4*)p, u1 = *(const float4*)(p + 4);
      float f[8] = {u0.x, u0.y, u0.z, u0.w, u1.x, u1.y, u1.z, u1.w};
      half8v hv;
#pragma unroll
      for (int i = 0; i < 8; i++) hv[i] = (_Float16)f[i];
      a[kc] = hv;
    } else {
      a[kc] = *(const half8v*)(aggp + (size_t)tileC * 2048 + (kc << 9) + lane * 8);
    }
  }

  float alpha = 1.f, beta = 0.f;
  if (!FIRST) {
    float sv = *skipv;
    alpha = 1.f / (1.f + __expf(-sv));
    beta = 1.f - alpha;
  }

  floatx4 acc1[8];
#pragma unroll
  for (int nt = 0; nt < 8; nt++) acc1[nt] = (floatx4){0.f, 0.f, 0.f, 0.f};
#pragma unroll
  for (int kc = 0; kc < 4; kc++) {
    half8v b[8];
#pragma unroll
    for (int nt = 0; nt < 8; nt++)
      b[nt] = *(const half8v*)(Wg1 + (size_t)nt * 2048 + (kc << 9) + lane * 8);
#pragma unroll
    for (int nt = 0; nt < 8; nt++)
      acc1[nt] = __builtin_amdgcn_mfma_f32_16x16x32_f16(a[kc], b[nt], acc1[nt], 0, 0, 0);
  }

  // epilogue1: per-64-col transpose; emit packed hbuf + LDS h-tile fragments
#pragma unroll
  for (int p = 0; p < 2; p++) {
    __syncthreads();
#pragma unroll
    for (int ntl = 0; ntl < 4; ntl++)
#pragma unroll
      for (int r = 0; r < 4; r++)
        myT[(q * 4 + r) * 68 + ntl * 16 + l16] = acc1[p * 4 + ntl][r];
    __syncthreads();
#pragma unroll
    for (int kc2 = 0; kc2 < 2; kc2++) {
      const float* rp = myT + mloc * 68 + kc2 * 32 + g * 8;
      floatx4 v0 = *(const floatx4*)rp;
      floatx4 v1 = *(const floatx4*)(rp + 4);
      float vals[8] = {v0[0], v0[1], v0[2], v0[3], v1[0], v1[1], v1[2], v1[3]};
      int col0 = p * 64 + kc2 * 32 + g * 8;
      size_t pbaseL = ((size_t)(tileC * 4 + (col0 >> 5)) << 9) + (size_t)lane * 8;
      if (FIRST) {
        float4 bb0 = *(const float4*)&bias[col0];
        float4 bb1 = *(const float4*)&bias[col0 + 4];
        float bbv[8] = {bb0.x, bb0.y, bb0.z, bb0.w, bb1.x, bb1.y, bb1.z, bb1.w};
#pragma unroll
        for (int j = 0; j < 8; j++) vals[j] = fmaxf(vals[j] + bbv[j], 0.f);
      } else {
        half8v hv = *(const half8v*)(hbuf + pbaseL);
#pragma unroll
        for (int j = 0; j < 8; j++)
          vals[j] = fmaxf(alpha * vals[j] + beta * (float)hv[j], 0.f);
      }
      half8v h8;
#pragma unroll
      for (int j = 0; j < 8; j++) h8[j] = (_Float16)vals[j];
      *(half8v*)(htile + (((p * 2 + kc2) << 9) + (g << 7) + (mloc << 3))) = h8;
      if (alive) *(half8v*)(hbuf + pbaseL) = h8;
    }
  }

  // GEMM2: kqv = h-tile @ Wcat (384 cols, 6 chunks of 64)
  for (int c = 0; c < 6; c++) {
    floatx4 acc2[4];
#pragma unroll
    for (int nt = 0; nt < 4; nt++) acc2[nt] = (floatx4){0.f, 0.f, 0.f, 0.f};
#pragma unroll
    for (int kc = 0; kc < 4; kc++) {
      half8v af = *(const half8v*)(htile + ((kc << 9) + lane * 8));
      half8v b[4];
#pragma unroll
      for (int nt = 0; nt < 4; nt++)
        b[nt] = *(const half8v*)(Wcat_l + (size_t)(c * 4 + nt) * 2048 + (kc << 9) + lane * 8);
#pragma unroll
      for (int nt = 0; nt < 4; nt++)
        acc2[nt] = __builtin_amdgcn_mfma_f32_16x16x32_f16(af, b[nt], acc2[nt], 0, 0, 0);
    }
    __syncthreads();
#pragma unroll
    for (int ntl = 0; ntl < 4; ntl++)
#pragma unroll
      for (int r = 0; r < 4; r++)
        myT[(q * 4 + r) * 68 + ntl * 16 + l16] = acc2[ntl][r];
    __syncthreads();
    if (alive) {
      int row = m0 + mloc;
#pragma unroll
      for (int kc2 = 0; kc2 < 2; kc2++) {
        const float* rp = myT + mloc * 68 + kc2 * 32 + g * 8;
        floatx4 v0 = *(const floatx4*)rp;
        floatx4 v1 = *(const floatx4*)(rp + 4);
        int col0 = c * 64 + kc2 * 32 + g * 8;
        int region = col0 >> 7;  // 0 kw, 1 q, 2 mv
        if (region == 1) {
          half8v h8;
#pragma unroll
          for (int j = 0; j < 4; j++) {
            h8[j] = (_Float16)v0[j];
            h8[j + 4] = (_Float16)v1[j];
          }
          *(half8v*)&qbuf[(size_t)row * 128 + (col0 - 128)] = h8;
        } else {
          int cc = col0 & 127;
          size_t base = (size_t)row * 256 + (size_t)(cc >> 2) * 8 + (region == 2 ? 4 : 0);
          half4v h0, h1;
#pragma unroll
          for (int j = 0; j < 4; j++) {
            h0[j] = (_Float16)v0[j];
            h1[j] = (_Float16)v1[j];
          }
          *(half4v*)&kwmv[base] = h0;
          *(half4v*)&kwmv[base + 8] = h1;
        }
      }
    }
  }
}

// ---------------- last Wa GEMM: hfinal = mix(agg @ Wa2, hold) (no relu) + hrow fp16
__global__ __launch_bounds__(256) void gemm_last(
    const _Float16* __restrict__ aggp, const _Float16* __restrict__ Wg1,
    const float* __restrict__ skipv, const _Float16* __restrict__ hbuf,
    float* __restrict__ hfinal, _Float16* __restrict__ hrow, int M) {
  int tid = threadIdx.x;
  int wave = tid >> 6, lane = tid & 63;
  int l16 = lane & 15, q = lane >> 4;
  int g = q, mloc = l16;
  int tile = blockIdx.x * 4 + wave;
  int m0 = tile * 16;
  bool alive = m0 < M;
  int tileC = alive ? tile : 0;

  __shared__ float ldsT_s[4][16 * 68];
  float* myT = ldsT_s[wave];

  half8v a[4];
#pragma unroll
  for (int kc = 0; kc < 4; kc++)
    a[kc] = *(const half8v*)(aggp + (size_t)tileC * 2048 + (kc << 9) + lane * 8);

  float sv = *skipv;
  float alpha = 1.f / (1.f + __expf(-sv));
  float beta = 1.f - alpha;

  floatx4 acc1[8];
#pragma unroll
  for (int nt = 0; nt < 8; nt++) acc1[nt] = (floatx4){0.f, 0.f, 0.f, 0.f};
#pragma unroll
  for (int kc = 0; kc < 4; kc++) {
    half8v b[8];
#pragma unroll
    for (int nt = 0; nt < 8; nt++)
      b[nt] = *(const half8v*)(Wg1 + (size_t)nt * 2048 + (kc << 9) + lane * 8);
#pragma unroll
    for (int nt = 0; nt < 8; nt++)
      acc1[nt] = __builtin_amdgcn_mfma_f32_16x16x32_f16(a[kc], b[nt], acc1[nt], 0, 0, 0);
  }

#pragma unroll
  for (int p = 0; p < 2; p++) {
    __syncthreads();
#pragma unroll
    for (int ntl = 0; ntl < 4; ntl++)
#pragma unroll
      for (int r = 0; r < 4; r++)
        myT[(q * 4 + r) * 68 + ntl * 16 + l16] = acc1[p * 4 + ntl][r];
    __syncthreads();
    if (alive) {
      int row = m0 + mloc;
#pragma unroll
      for (int kc2 = 0; kc2 < 2; kc2++) {
        const float* rp = myT + mloc * 68 + kc2 * 32 + g * 8;
        floatx4 v0 = *(const floatx4*)rp;
        floatx4 v1 = *(const floatx4*)(rp + 4);
        float vals[8] = {v0[0], v0[1], v0[2], v0[3], v1[0], v1[1], v1[2], v1[3]};
        int col0 = p * 64 + kc2 * 32 + g * 8;
        size_t pbase = ((size_t)(tile * 4 + (col0 >> 5)) << 9) + (size_t)lane * 8;
        half8v hv = *(const half8v*)(hbuf + pbase);
#pragma unroll
        for (int j = 0; j < 8; j++) vals[j] = alpha * vals[j] + beta * (float)hv[j];
        *(float4*)&hfinal[(size_t)row * 128 + col0] =
            make_float4(vals[0], vals[1], vals[2], vals[3]);
        *(float4*)&hfinal[(size_t)row * 128 + col0 + 4] =
            make_float4(vals[4], vals[5], vals[6], vals[7]);
        half8v h8;
#pragma unroll
        for (int j = 0; j < 8; j++) h8[j] = (_Float16)vals[j];
        *(half8v*)&hrow[(size_t)row * 128 + col0] = h8;
      }
    }
  }
}

// ---------------- fused predictor: Z=h[a]*h[b] -> W1+leaky -> W2+leaky -> dot W3
__global__ __launch_bounds__(256) void pred_fused(
    const _Float16* __restrict__ hrow,
    const int* __restrict__ ps, const int* __restrict__ pd,
    const int* __restrict__ ns, const int* __restrict__ nd,
    const _Float16* __restrict__ W1f, const float* __restrict__ b1,
    const _Float16* __restrict__ W2f, const float* __restrict__ b2,
    const float* __restrict__ W3, const float* __restrict__ b3,
    float* __restrict__ outd, int M) {
  int tid = threadIdx.x;
  int wave = tid >> 6, lane = tid & 63;
  int l16 = lane & 15, q = lane >> 4;
  int g = q, mloc = l16;
  int tile = blockIdx.x * 4 + wave;
  int m0 = tile * 16;
  bool alive = m0 < M;

  __shared__ _Float16 t1_s[4][1024];
  __shared__ float ldsT_s[4][16 * 68];
  _Float16* t1tile = t1_s[wave];
  float* myT = ldsT_s[wave];

  int gr = min(m0 + l16, M - 1);
  bool pos = gr < N_PAIRS;
  int idx = pos ? gr : gr - N_PAIRS;
  int pa = pos ? ps[idx] : ns[idx];
  int pb = pos ? pd[idx] : nd[idx];

  half8v a[4];
#pragma unroll
  for (int kc = 0; kc < 4; kc++) {
    int kbase = kc * 32 + q * 8;
    half8v ha = *(const half8v*)(hrow + (size_t)pa * 128 + kbase);
    half8v hb = *(const half8v*)(hrow + (size_t)pb * 128 + kbase);
    a[kc] = ha * hb;
  }

  floatx4 acc1[4];
#pragma unroll
  for (int nt = 0; nt < 4; nt++) acc1[nt] = (floatx4){0.f, 0.f, 0.f, 0.f};
#pragma unroll
  for (int kc = 0; kc < 4; kc++) {
    half8v b[4];
#pragma unroll
    for (int nt = 0; nt < 4; nt++)
      b[nt] = *(const half8v*)(W1f + (size_t)nt * 2048 + (kc << 9) + lane * 8);
#pragma unroll
    for (int nt = 0; nt < 4; nt++)
      acc1[nt] = __builtin_amdgcn_mfma_f32_16x16x32_f16(a[kc], b[nt], acc1[nt], 0, 0, 0);
  }

  // epilogue1: bias+leaky -> per-wave T1 fragments (16 rows x 64 k)
  __syncthreads();
#pragma unroll
  for (int ntl = 0; ntl < 4; ntl++)
#pragma unroll
    for (int r = 0; r < 4; r++)
      myT[(q * 4 + r) * 68 + ntl * 16 + l16] = acc1[ntl][r];
  __syncthreads();
#pragma unroll
  for (int kc2 = 0; kc2 < 2; kc2++) {
    const float* rp = myT + mloc * 68 + kc2 * 32 + g * 8;
    floatx4 v0 = *(const floatx4*)rp;
    floatx4 v1 = *(const floatx4*)(rp + 4);
    float vals[8] = {v0[0], v0[1], v0[2], v0[3], v1[0], v1[1], v1[2], v1[3]};
    int col0 = kc2 * 32 + g * 8;
    float4 bb0 = *(const float4*)&b1[col0];
    float4 bb1 = *(const float4*)&b1[col0 + 4];
    float bbv[8] = {bb0.x, bb0.y, bb0.z, bb0.w, bb1.x, bb1.y, bb1.z, bb1.w};
    half8v h8;
#pragma unroll
    for (int j = 0; j < 8; j++) {
      float v = vals[j] + bbv[j];
      v = v > 0.f ? v : 0.2f * v;
      h8[j] = (_Float16)v;
    }
    *(half8v*)(t1tile + ((kc2 << 9) + (g << 7) + (mloc << 3))) = h8;
  }

  // GEMM2: T1 @ W2 (K=64, N=32) + leaky + dot W3
  floatx4 acc2[2];
#pragma unroll
  for (int nt = 0; nt < 2; nt++) acc2[nt] = (floatx4){0.f, 0.f, 0.f, 0.f};
#pragma unroll
  for (int kc = 0; kc < 2; kc++) {
    half8v af = *(const half8v*)(t1tile + ((kc << 9) + lane * 8));
    half8v b[2];
#pragma unroll
    for (int nt = 0; nt < 2; nt++)
      b[nt] = *(const half8v*)(W2f + (size_t)nt * 1024 + (kc << 9) + lane * 8);
#pragma unroll
    for (int nt = 0; nt < 2; nt++)
      acc2[nt] = __builtin_amdgcn_mfma_f32_16x16x32_f16(af, b[nt], acc2[nt], 0, 0, 0);
  }

  float bw[2], wv[2];
#pragma unroll
  for (int nt = 0; nt < 2; nt++) {
    int col = nt * 16 + l16;
    bw[nt] = b2[col];
    wv[nt] = W3[col];
  }
  float b3v = b3[0];
#pragma unroll
  for (int r = 0; r < 4; r++) {
    float partial = 0.f;
#pragma unroll
    for (int nt = 0; nt < 2; nt++) {
      float v = acc2[nt][r] + bw[nt];
      v = v > 0.f ? v : 0.2f * v;
      partial += v * wv[nt];
    }
    partial += __shfl_xor(partial, 1);
    partial += __shfl_xor(partial, 2);
    partial += __shfl_xor(partial, 4);
    partial += __shfl_xor(partial, 8);
    int row = m0 + q * 4 + r;
    if (l16 == 0 && alive && row < M) outd[row] = partial + b3v;
  }
}

// ---------------- per-destination online-softmax aggregation
// One node per half-wave; gathers staged via global_load_lds DMA (no VGPRs held
// in flight). 2 LDS slabs/wave ping-pong with counted vmcnt(4) -> one 4KB
// chunk-pair always in flight while another is consumed. Edge meta (src,w)
// block-DMA'd per node-pair into an LDS 64-edge window; inner loop issues ONLY
// the 4 gather DMAs per iteration so vmcnt counting is exact.
#define WAITV4 { asm volatile("s_waitcnt vmcnt(4)" ::: "memory"); __builtin_amdgcn_sched_barrier(0); }
#define WAITV0 { asm volatile("s_waitcnt vmcnt(0)" ::: "memory"); __builtin_amdgcn_sched_barrier(0); }
#define LGKM0  { asm volatile("s_waitcnt lgkmcnt(0)" ::: "memory"); __builtin_amdgcn_sched_barrier(0); }

#define GLD16(G, L)                                                        \
  __builtin_amdgcn_global_load_lds(                                        \
      (const __attribute__((address_space(1))) void*)(G),                  \
      (__attribute__((address_space(3))) void*)(L), 16, 0, 0)
#define GLD4(G, L)                                                         \
  __builtin_amdgcn_global_load_lds(                                        \
      (const __attribute__((address_space(1))) void*)(G),                  \
      (__attribute__((address_space(3))) void*)(L), 4, 0, 0)

// meta window: 64 edges per half. lane l loads entry l (per-lane global addr,
// lane*4 LDS offset applied by HW).
#define META_DMA(B, BA, BB)                                                \
  {                                                                        \
    GLD4(em + ((size_t)(BA) + lane) * 2,     &meta_s[wave][B][0][0][0]);   \
    GLD4(em + ((size_t)(BA) + lane) * 2 + 1, &meta_s[wave][B][0][1][0]);   \
    GLD4(em + ((size_t)(BB) + lane) * 2,     &meta_s[wave][B][1][0][0]);   \
    GLD4(em + ((size_t)(BB) + lane) * 2 + 1, &meta_s[wave][B][1][1][0]);   \
  }

// gather chunk (4 edges) into slab P: per-lane global addr = row[src]+c4*16B,
// wave-uniform LDS base (HW adds lane*16).
#define GATHER_DMA(P, S)                                                   \
  _Pragma("unroll") for (int i = 0; i < 4; i++)                            \
      GLD16(kwmv + (size_t)max(S[i], 0) * 256 + lofs, &slab_s[wave][P][i][0][0]);

#define READ_SRCS(B, WL, S)                                                \
  _Pragma("unroll") for (int i = 0; i < 4; i++)                            \
      S[i] = meta_s[wave][B][half][0][(WL) * 4 + i];

__global__ __launch_bounds__(256) void edge_agg_kernel(
    const _Float16* __restrict__ kwmv, const _Float16* __restrict__ qbuf,
    const int* __restrict__ poffs, const int* __restrict__ deg,
    const int2* __restrict__ eld, const int* __restrict__ perm,
    _Float16* __restrict__ agg, int npairs) {
  __shared__ __align__(16) _Float16 slab_s[4][2][4][64][8];  // 32 KB
  __shared__ int meta_s[4][2][2][2][64];                     // 8 KB
  int tid = threadIdx.x;
  int wave = tid >> 6, lane = tid & 63;
  int half = lane >> 5, c4 = lane & 31;
  int ch = c4 << 2;
  size_t lofs = (size_t)c4 * 8;
  const int* em = (const int*)eld;

  // zero slabs once: stale reads (masked lanes) must be finite
  {
    half8v z = {};
    _Float16* sl = &slab_s[0][0][0][0][0];
    for (int i = tid; i < 2048; i += 256) *(half8v*)(sl + (size_t)i * 8) = z;
  }
  __syncthreads();

  int ws = blockIdx.x * 4 + wave;
  int stride = gridDim.x * 4;
  if (ws >= npairs) return;

  // preload first pair's meta into buffer 0
  {
    int nA = perm[2 * ws], nB = perm[2 * ws + 1];
    META_DMA(0, poffs[nA], poffs[nB]);
  }

  for (int pr = ws, k = 0; pr < npairs; pr += stride, k ^= 1) {
    int nodeA = perm[2 * pr], nodeB = perm[2 * pr + 1];
    int begA = poffs[nodeA], begB = poffs[nodeB];
    int node = half ? nodeB : nodeA;
    int beg = half ? begB : begA;
    int dg = deg[node];
    int nc = (dg + 3) >> 2;
    int ncU = max(nc, __shfl_xor(nc, 32));
    half4v qv = *(const half4v*)&qbuf[(size_t)node * 128 + ch];
    (void)beg;
    WAITV0;  // meta(k) arrived; all prior traffic drained (exact counts below)
    half2v q01 = {qv[0], qv[1]}, q23 = {qv[2], qv[3]};
    // prefetch next pair's meta (older than all gathers -> never blocks counts)
    int prn = pr + stride;
    if (prn < npairs) {
      int a2 = perm[2 * prn], b2 = perm[2 * prn + 1];
      META_DMA(k ^ 1, poffs[a2], poffs[b2]);
    }
    float m = -1e30f, s = 0.f;
    float a0 = 0.f, a1 = 0.f, a2f = 0.f, a3 = 0.f;
    int wbase = 0;
    // prologue: issue chunks 0,1
    if (ncU > 0) {
      int s4[4];
      READ_SRCS(k, 0, s4);
      GATHER_DMA(0, s4);
      if (ncU > 1) {
        READ_SRCS(k, 1, s4);
        GATHER_DMA(1, s4);
      }
    }
    for (int c = 0; c < ncU; ++c) {
      int p = c & 1;
      if (c + 1 < ncU) { WAITV4 } else { WAITV0 }
      // consume-side LDS reads (old window / slab p)
      half8v G[4];
#pragma unroll
      for (int i = 0; i < 4; i++)
        G[i] = *(const half8v*)&slab_s[wave][p][i][lane][0];
      int wl = c - wbase;
      float wf[4];
#pragma unroll
      for (int i = 0; i < 4; i++)
        wf[i] = __int_as_float(meta_s[wave][k][half][1][wl * 4 + i]);
      LGKM0;  // G,wf in regs before slab p is overwritten / window refilled
      if (c + 2 < ncU) {
        if (c + 2 - wbase >= 16) {  // window refill (cold; rebase to chunk c)
          WAITV0;
          META_DMA(k, begA + c * 4, begB + c * 4);
          wbase = c;
          WAITV0;
        }
        int s4[4];
        READ_SRCS(k, c + 2 - wbase, s4);
        GATHER_DMA(p, s4);
      }
      // compute chunk c
      float p4[4];
#pragma unroll
      for (int i = 0; i < 4; i++) {
        half2v k01 = {G[i][0], G[i][1]}, k23 = {G[i][2], G[i][3]};
        float d = __builtin_amdgcn_fdot2(
            k01, q01, __builtin_amdgcn_fdot2(k23, q23, 0.f, false), false);
        d += __shfl_xor(d, 1);
        d += __shfl_xor(d, 2);
        p4[i] = (c * 4 + i < dg) ? d : -1e30f;
      }
      float nm = m;
#pragma unroll
      for (int i = 0; i < 4; i++) nm = fmaxf(nm, p4[i]);
      float sc = __expf(m - nm);
      float tt[4], ssum = 0.f;
#pragma unroll
      for (int i = 0; i < 4; i++) {
        tt[i] = __expf(p4[i] - nm);
        ssum += tt[i];
      }
      s = s * sc + ssum;
      a0 *= sc; a1 *= sc; a2f *= sc; a3 *= sc;
#pragma unroll
      for (int i = 0; i < 4; i++) {
        float w = (c * 4 + i < dg) ? wf[i] : 0.f;
        float f = tt[i] * w;
        a0 += f * (float)G[i][4];
        a1 += f * (float)G[i][5];
        a2f += f * (float)G[i][6];
        a3 += f * (float)G[i][7];
      }
      m = nm;
    }
    float inv = (s > 0.f) ? 1.f / s : 0.f;
    half4v out4;
    out4[0] = (_Float16)(a0 * inv);
    out4[1] = (_Float16)(a1 * inv);
    out4[2] = (_Float16)(a2f * inv);
    out4[3] = (_Float16)(a3 * inv);
    *(half4v*)&agg[packA(node, ch, 128)] = out4;
  }
}

extern "C" void kernel_launch(void* const* d_in, const int* in_sizes, int n_in,
                              void* d_out, int out_size, void* d_ws, size_t ws_size,
                              hipStream_t stream) {
  const float* x        = (const float*)d_in[0];
  const int*   edge_src = (const int*)d_in[1];
  const int*   edge_dst = (const int*)d_in[2];
  const float* edge_w   = (const float*)d_in[3];
  const int*   pos_src  = (const int*)d_in[4];
  const int*   pos_dst  = (const int*)d_in[5];
  const int*   neg_src  = (const int*)d_in[6];
  const int*   neg_dst  = (const int*)d_in[7];
  const float* W_in     = (const float*)d_in[8];
  const float* b_in     = (const float*)d_in[9];
  const float* Wk       = (const float*)d_in[10];
  const float* Wq       = (const float*)d_in[11];
  const float* Wv       = (const float*)d_in[12];
  const float* att_w    = (const float*)d_in[13];
  const float* msg_w    = (const float*)d_in[14];
  const float* pri      = (const float*)d_in[15];
  const float* Wa       = (const float*)d_in[16];
  const float* skip     = (const float*)d_in[17];
  const float* W1       = (const float*)d_in[18];
  const float* b1       = (const float*)d_in[19];
  const float* W2       = (const float*)d_in[20];
  const float* b2       = (const float*)d_in[21];
  const float* W3       = (const float*)d_in[22];
  const float* b3       = (const float*)d_in[23];
  float* out = (float*)d_out;

  // ---- workspace layout (bytes), ~91 MB
  char* W = (char*)d_ws;
  _Float16*  qbuf   = (_Float16*)(W + 0);          // 12,800,000
  _Float16*  kwmv   = (_Float16*)(W + 12800000);   // 25,600,000
  _Float16*  hbuf   = (_Float16*)(W + 38400000);   // 12,800,000 (packed h)
  _Float16*  agg    = (_Float16*)(W + 51200000);   // 12,800,000
  _Float16*  Wint   = (_Float16*)(W + 64000000);   // 32,768
  _Float16*  Wcat   = (_Float16*)(W + 64032768);   // 294,912
  _Float16*  Waf    = (_Float16*)(W + 64327680);   // 98,304
  _Float16*  W1f    = (_Float16*)(W + 64425984);   // 16,384
  _Float16*  W2f    = (_Float16*)(W + 64442368);   // 8,192
  int2*      eld    = (int2*)(W + 64450560);       // 12,800,000 (padded-4 edges)
  int*       deg    = (int*)(W + 77250560);        // 200,000
  int*       poffs  = (int*)(W + 77450560);        // 200,016
  int*       cursor = (int*)(W + 77650576);        // 200,000
  int*       perm   = (int*)(W + 77850576);        // 200,000
  int*       bsum   = (int*)(W + 78050576);        // 1,024
  int*       boff   = (int*)(W + 78051600);        // 1,024
  int*       bh     = (int*)(W + 78052624);        // 1,024
  int*       bcur   = (int*)(W + 78053648);        // 1,024
  _Float16*  hrow   = (_Float16*)(W + 78054912);   // 12,800,000 (fp16 row-major hfinal)
  float* hfinal = out + 2 * N_PAIRS;

  hipMemsetAsync(deg, 0, N_NODES * sizeof(int), stream);
  hipMemsetAsync(bh, 0, 1024, stream);
  // sentinel: src=-1. pad-4 worst case: E + 3*N slots = 7.6MB (+window overrun)
  hipMemsetAsync(eld, 0xFF, 8000000, stream);

  wprep_kernel<<<880, 256, 0, stream>>>(W_in, Wk, Wq, Wv, att_w, msg_w, pri, Wa, W1, W2,
                                        Wint, Wcat, Waf, W1f, W2f);
  hist_kernel<<<(N_EDGES + 255) / 256, 256, 0, stream>>>(edge_dst, deg, N_EDGES);
  scanA_kernel<<<196, 256, 0, stream>>>(deg, poffs, bsum, N_NODES);
  scanB_kernel<<<1, 256, 0, stream>>>(bsum, boff, poffs, 196, N_NODES);
  scanC_kernel<<<196, 256, 0, stream>>>(poffs, boff, cursor, N_NODES);
  scatter_kernel<<<(N_EDGES + 255) / 256, 256, 0, stream>>>(
      edge_src, edge_dst, edge_w, cursor, eld, N_EDGES);
  bhist_kernel<<<196, 256, 0, stream>>>(deg, bh, N_NODES);
  bscan_kernel<<<1, 256, 0, stream>>>(bh, bcur);
  bscatter_kernel<<<196, 256, 0, stream>>>(deg, bcur, perm, N_NODES);

  // layer 0: x -> h_in (relu proj) -> kqv0
  fused_layer<1><<<782, 256, 0, stream>>>(x, nullptr, Wint, b_in, nullptr, hbuf,
                                          Wcat, kwmv, qbuf, N_NODES);
  edge_agg_kernel<<<1024, 256, 0, stream>>>(kwmv, qbuf, poffs, deg, eld, perm,
                                            agg, N_NODES / 2);
  // layer 1: agg0 -> h0 (skip-mix+relu) -> kqv1
  fused_layer<0><<<782, 256, 0, stream>>>(nullptr, agg, Waf, nullptr, skip + 0, hbuf,
                                          Wcat + 49152, kwmv, qbuf, N_NODES);
  edge_agg_kernel<<<1024, 256, 0, stream>>>(kwmv, qbuf, poffs, deg, eld, perm,
                                            agg, N_NODES / 2);
  // layer 2: agg1 -> h1 (skip-mix+relu) -> kqv2
  fused_layer<0><<<782, 256, 0, stream>>>(nullptr, agg, Waf + 16384, nullptr, skip + 1,
                                          hbuf, Wcat + 98304, kwmv, qbuf, N_NODES);
  edge_agg_kernel<<<1024, 256, 0, stream>>>(kwmv, qbuf, poffs, eld ? deg : deg, eld, perm,
                                            agg, N_NODES / 2);
  // final: agg2 -> hfinal (skip-mix, no relu) + hrow fp16
  gemm_last<<<782, 256, 0, stream>>>(agg, Waf + 32768, skip + 2, hbuf,
                                     hfinal, hrow, N_NODES);
  // predictor (fully fused)
  pred_fused<<<3125, 256, 0, stream>>>(hrow, pos_src, pos_dst, neg_src, neg_dst,
                                       W1f, b1, W2f, b2, W3, b3, out, 2 * N_PAIRS);
}

// Round 6
// 549.216 us; speedup vs baseline: 1.6921x; 1.0223x over previous
//
#include <hip/hip_runtime.h>
#include <cstddef>

#define N_NODES 50000
#define N_EDGES 800000
#define N_PAIRS 100000

typedef float floatx4 __attribute__((ext_vector_type(4)));
typedef _Float16 half2v __attribute__((ext_vector_type(2)));
typedef _Float16 half4v __attribute__((ext_vector_type(4)));
typedef _Float16 half8v __attribute__((ext_vector_type(8)));

// intra-wave LDS fence: all LDS buffers in the GEMM kernels are PER-WAVE, so
// cross-wave __syncthreads (which drains vmcnt(0) too) is unnecessary. DS ops
// from one wave complete in order; lgkmcnt(0) covers the RAW edge. sched_barrier
// pins ordering at the MIR level (rule #18).
#define LWAIT { asm volatile("s_waitcnt lgkmcnt(0)" ::: "memory"); __builtin_amdgcn_sched_barrier(0); }

// packed MFMA A/B-fragment layout: [tile16][kchunk32][lane][8] (fp16)
__device__ inline size_t packA(int m, int k, int K) {
  return ((size_t)((m >> 4) * (K >> 5) + (k >> 5)) << 9) +
         ((((unsigned)k >> 3) & 3) << 7) + ((m & 15) << 3) + (k & 7);
}

// ---------------- weight prep (fold + transpose + pack, fp16)
__device__ inline float fold_val(int l, int r, int j, const float* Wk, const float* Wq,
                                 const float* Wv, const float* att, const float* msg,
                                 const float* pri) {
  if (j >= 128 && j < 256) return Wq[(l * 128 + r) * 128 + (j - 128)];
  int jj = j & 127, hh = jj >> 4, e = jj & 15;
  const float* W = (j < 128) ? Wk : Wv;
  const float* T = (j < 128) ? att : msg;
  float s = 0.f;
#pragma unroll
  for (int d = 0; d < 16; d++)
    s += W[(l * 128 + r) * 128 + hh * 16 + d] * T[((l * 8 + hh) * 16 + d) * 16 + e];
  if (j < 128) s *= pri[l * 8 + hh] * 0.25f;
  return s;
}

__global__ void wprep_kernel(const float* __restrict__ W_in, const float* __restrict__ Wk,
                             const float* __restrict__ Wq, const float* __restrict__ Wv,
                             const float* __restrict__ att, const float* __restrict__ msg,
                             const float* __restrict__ pri, const float* __restrict__ Wa,
                             const float* __restrict__ W1, const float* __restrict__ W2,
                             _Float16* Wint, _Float16* Wcat, _Float16* Waf,
                             _Float16* W1f, _Float16* W2f) {
  int gid = blockIdx.x * 256 + threadIdx.x;
  float v;
  _Float16* dt;
  size_t o;
  if (gid < 16384) {
    int n = gid >> 7, k = gid & 127;
    v = W_in[k * 128 + n];
    dt = Wint; o = packA(n, k, 128);
  } else if (gid < 163840) {
    int t = gid - 16384;
    int l = t / 49152, u = t - l * 49152;
    int n = u >> 7, k = u & 127;
    v = fold_val(l, k, n, Wk, Wq, Wv, att, msg, pri);
    dt = Wcat + (size_t)l * 49152;
    o = packA(n, k, 128);
  } else if (gid < 212992) {
    int t = gid - 163840;
    int l = t / 16384, u = t & 16383;
    int n = u >> 7, k = u & 127;
    v = Wa[(size_t)l * 16384 + k * 128 + n];
    dt = Waf + (size_t)l * 16384;
    o = packA(n, k, 128);
  } else if (gid < 221184) {
    int u = gid - 212992;
    int n = u >> 7, k = u & 127;
    v = W1[k * 64 + n];
    dt = W1f; o = packA(n, k, 128);
  } else if (gid < 225280) {
    int u = gid - 221184;
    int n = u >> 6, k = u & 63;
    v = (n < 32) ? W2[k * 32 + n] : 0.f;
    dt = W2f; o = packA(n, k, 64);
  } else {
    return;
  }
  dt[o] = (_Float16)v;
}

// ---------------- CSR build (padded to multiple of 8 per node)
__global__ void hist_kernel(const int* __restrict__ dst, int* __restrict__ deg, int E) {
  int g = blockIdx.x * blockDim.x + threadIdx.x;
  if (g < E) atomicAdd(&deg[dst[g]], 1);
}

__global__ void scanA_kernel(const int* __restrict__ deg, int* __restrict__ offs,
                             int* __restrict__ bsum, int n) {
  __shared__ int sm[256];
  int t = threadIdx.x;
  int i = blockIdx.x * 256 + t;
  // pad each node's slot count to a multiple of 8 (half-wave chunk granularity)
  int v = (i < n) ? ((deg[i] + 7) & ~7) : 0;
  sm[t] = v;
  __syncthreads();
  for (int off = 1; off < 256; off <<= 1) {
    int u = (t >= off) ? sm[t - off] : 0;
    __syncthreads();
    sm[t] += u;
    __syncthreads();
  }
  if (i < n) offs[i] = sm[t] - v;
  if (t == 255) bsum[blockIdx.x] = sm[255];
}

__global__ void scanB_kernel(const int* __restrict__ bsum, int* __restrict__ boff,
                             int* __restrict__ offs, int nb, int n) {
  __shared__ int sm[256];
  int t = threadIdx.x;
  int v = (t < nb) ? bsum[t] : 0;
  sm[t] = v;
  __syncthreads();
  for (int off = 1; off < 256; off <<= 1) {
    int u = (t >= off) ? sm[t - off] : 0;
    __syncthreads();
    sm[t] += u;
    __syncthreads();
  }
  boff[t] = sm[t] - v;
  if (t == nb - 1) offs[n] = sm[t];
}

__global__ void scanC_kernel(int* __restrict__ offs, const int* __restrict__ boff,
                             int* __restrict__ cursor, int n) {
  int i = blockIdx.x * 256 + threadIdx.x;
  if (i < n) {
    int o = offs[i] + boff[blockIdx.x];
    offs[i] = o;
    cursor[i] = o;
  }
}

__global__ void scatter_kernel(const int* __restrict__ src, const int* __restrict__ dst,
                               const float* __restrict__ w, int* __restrict__ cursor,
                               int2* __restrict__ eld, int E) {
  int g = blockIdx.x * blockDim.x + threadIdx.x;
  if (g < E) {
    int d = dst[g];
    int p = atomicAdd(&cursor[d], 1);
    eld[p] = make_int2(src[g], __float_as_int(w[g]));
  }
}

// ---------------- degree-descending node permutation (counting sort, 256 buckets)
__global__ void bhist_kernel(const int* __restrict__ deg, int* __restrict__ bh, int n) {
  __shared__ int lh[256];
  int t = threadIdx.x;
  lh[t] = 0;
  __syncthreads();
  int i = blockIdx.x * 256 + t;
  if (i < n) atomicAdd(&lh[min(deg[i], 255)], 1);
  __syncthreads();
  if (lh[t]) atomicAdd(&bh[t], lh[t]);
}
__global__ void bscan_kernel(const int* __restrict__ bh, int* __restrict__ bcur) {
  __shared__ int sm[256];
  int t = threadIdx.x;
  int v = bh[255 - t];
  sm[t] = v;
  __syncthreads();
  for (int off = 1; off < 256; off <<= 1) {
    int u = (t >= off) ? sm[t - off] : 0;
    __syncthreads();
    sm[t] += u;
    __syncthreads();
  }
  bcur[255 - t] = sm[t] - v;
}
__global__ void bscatter_kernel(const int* __restrict__ deg, int* __restrict__ bcur,
                                int* __restrict__ perm, int n) {
  __shared__ int lh[256], lbase[256];
  int t = threadIdx.x;
  lh[t] = 0;
  __syncthreads();
  int i = blockIdx.x * 256 + t;
  int b = 0, local = 0;
  if (i < n) {
    b = min(deg[i], 255);
    local = atomicAdd(&lh[b], 1);
  }
  __syncthreads();
  int cnt = lh[t];
  lbase[t] = cnt ? atomicAdd(&bcur[t], cnt) : 0;
  __syncthreads();
  if (i < n) perm[lbase[b] + local] = i;
}

// ---------------- fused layer kernel: GEMM1 (h) -> LDS fragments -> GEMM2 (kqv)
// All LDS is per-wave -> no __syncthreads; intra-wave LWAIT fences only.
template <int FIRST>
__global__ __launch_bounds__(256) void fused_layer(
    const float* __restrict__ x, const _Float16* __restrict__ aggp,
    const _Float16* __restrict__ Wg1, const float* __restrict__ bias,
    const float* __restrict__ skipv, _Float16* __restrict__ hbuf,
    const _Float16* __restrict__ Wcat_l,
    _Float16* __restrict__ kwmv, _Float16* __restrict__ qbuf, int M) {
  int tid = threadIdx.x;
  int wave = tid >> 6, lane = tid & 63;
  int l16 = lane & 15, q = lane >> 4;
  int g = q, mloc = l16;
  int tile = blockIdx.x * 4 + wave;
  int m0 = tile * 16;
  bool alive = m0 < M;
  int tileC = alive ? tile : 0;

  __shared__ _Float16 htile_s[4][2048];
  __shared__ float ldsT_s[4][16 * 68];
  _Float16* htile = htile_s[wave];
  float* myT = ldsT_s[wave];

  // GEMM1 A fragments
  half8v a[4];
#pragma unroll
  for (int kc = 0; kc < 4; kc++) {
    if (FIRST) {
      int row = min(m0 + l16, M - 1);
      const float* p = x + (size_t)row * 128 + kc * 32 + q * 8;
      float4 u0 = *(const float4*)p, u1 = *(const float4*)(p + 4);
      float f[8] = {u0.x, u0.y, u0.z, u0.w, u1.x, u1.y, u1.z, u1.w};
      half8v hv;
#pragma unroll
      for (int i = 0; i < 8; i++) hv[i] = (_Float16)f[i];
      a[kc] = hv;
    } else {
      a[kc] = *(const half8v*)(aggp + (size_t)tileC * 2048 + (kc << 9) + lane * 8);
    }
  }

  float alpha = 1.f, beta = 0.f;
  if (!FIRST) {
    float sv = *skipv;
    alpha = 1.f / (1.f + __expf(-sv));
    beta = 1.f - alpha;
  }

  floatx4 acc1[8];
#pragma unroll
  for (int nt = 0; nt < 8; nt++) acc1[nt] = (floatx4){0.f, 0.f, 0.f, 0.f};
#pragma unroll
  for (int kc = 0; kc < 4; kc++) {
    half8v b[8];
#pragma unroll
    for (int nt = 0; nt < 8; nt++)
      b[nt] = *(const half8v*)(Wg1 + (size_t)nt * 2048 + (kc << 9) + lane * 8);
#pragma unroll
    for (int nt = 0; nt < 8; nt++)
      acc1[nt] = __builtin_amdgcn_mfma_f32_16x16x32_f16(a[kc], b[nt], acc1[nt], 0, 0, 0);
  }

  // epilogue1: per-64-col transpose; emit packed hbuf + LDS h-tile fragments
#pragma unroll
  for (int p = 0; p < 2; p++) {
#pragma unroll
    for (int ntl = 0; ntl < 4; ntl++)
#pragma unroll
      for (int r = 0; r < 4; r++)
        myT[(q * 4 + r) * 68 + ntl * 16 + l16] = acc1[p * 4 + ntl][r];
    LWAIT;
#pragma unroll
    for (int kc2 = 0; kc2 < 2; kc2++) {
      const float* rp = myT + mloc * 68 + kc2 * 32 + g * 8;
      floatx4 v0 = *(const floatx4*)rp;
      floatx4 v1 = *(const floatx4*)(rp + 4);
      float vals[8] = {v0[0], v0[1], v0[2], v0[3], v1[0], v1[1], v1[2], v1[3]};
      int col0 = p * 64 + kc2 * 32 + g * 8;
      size_t pbaseL = ((size_t)(tileC * 4 + (col0 >> 5)) << 9) + (size_t)lane * 8;
      if (FIRST) {
        float4 bb0 = *(const float4*)&bias[col0];
        float4 bb1 = *(const float4*)&bias[col0 + 4];
        float bbv[8] = {bb0.x, bb0.y, bb0.z, bb0.w, bb1.x, bb1.y, bb1.z, bb1.w};
#pragma unroll
        for (int j = 0; j < 8; j++) vals[j] = fmaxf(vals[j] + bbv[j], 0.f);
      } else {
        half8v hv = *(const half8v*)(hbuf + pbaseL);
#pragma unroll
        for (int j = 0; j < 8; j++)
          vals[j] = fmaxf(alpha * vals[j] + beta * (float)hv[j], 0.f);
      }
      half8v h8;
#pragma unroll
      for (int j = 0; j < 8; j++) h8[j] = (_Float16)vals[j];
      *(half8v*)(htile + (((p * 2 + kc2) << 9) + (g << 7) + (mloc << 3))) = h8;
      if (alive) *(half8v*)(hbuf + pbaseL) = h8;
    }
    LWAIT;  // myT reads done before next phase overwrites (WAR; in-order DS)
  }

  // GEMM2: kqv = h-tile @ Wcat (384 cols, 6 chunks of 64)
  LWAIT;  // htile writes visible
  for (int c = 0; c < 6; c++) {
    floatx4 acc2[4];
#pragma unroll
    for (int nt = 0; nt < 4; nt++) acc2[nt] = (floatx4){0.f, 0.f, 0.f, 0.f};
#pragma unroll
    for (int kc = 0; kc < 4; kc++) {
      half8v af = *(const half8v*)(htile + ((kc << 9) + lane * 8));
      half8v b[4];
#pragma unroll
      for (int nt = 0; nt < 4; nt++)
        b[nt] = *(const half8v*)(Wcat_l + (size_t)(c * 4 + nt) * 2048 + (kc << 9) + lane * 8);
#pragma unroll
      for (int nt = 0; nt < 4; nt++)
        acc2[nt] = __builtin_amdgcn_mfma_f32_16x16x32_f16(af, b[nt], acc2[nt], 0, 0, 0);
    }
#pragma unroll
    for (int ntl = 0; ntl < 4; ntl++)
#pragma unroll
      for (int r = 0; r < 4; r++)
        myT[(q * 4 + r) * 68 + ntl * 16 + l16] = acc2[ntl][r];
    LWAIT;
    if (alive) {
      int row = m0 + mloc;
#pragma unroll
      for (int kc2 = 0; kc2 < 2; kc2++) {
        const float* rp = myT + mloc * 68 + kc2 * 32 + g * 8;
        floatx4 v0 = *(const floatx4*)rp;
        floatx4 v1 = *(const floatx4*)(rp + 4);
        int col0 = c * 64 + kc2 * 32 + g * 8;
        int region = col0 >> 7;  // 0 kw, 1 q, 2 mv
        if (region == 1) {
          half8v h8;
#pragma unroll
          for (int j = 0; j < 4; j++) {
            h8[j] = (_Float16)v0[j];
            h8[j + 4] = (_Float16)v1[j];
          }
          *(half8v*)&qbuf[(size_t)row * 128 + (col0 - 128)] = h8;
        } else {
          int cc = col0 & 127;
          size_t base = (size_t)row * 256 + (size_t)(cc >> 2) * 8 + (region == 2 ? 4 : 0);
          half4v h0, h1;
#pragma unroll
          for (int j = 0; j < 4; j++) {
            h0[j] = (_Float16)v0[j];
            h1[j] = (_Float16)v1[j];
          }
          *(half4v*)&kwmv[base] = h0;
          *(half4v*)&kwmv[base + 8] = h1;
        }
      }
    }
    LWAIT;  // myT reads done before next c overwrites
  }
}

// ---------------- last Wa GEMM: hfinal = mix(agg @ Wa2, hold) (no relu) + hrow fp16
__global__ __launch_bounds__(256) void gemm_last(
    const _Float16* __restrict__ aggp, const _Float16* __restrict__ Wg1,
    const float* __restrict__ skipv, const _Float16* __restrict__ hbuf,
    float* __restrict__ hfinal, _Float16* __restrict__ hrow, int M) {
  int tid = threadIdx.x;
  int wave = tid >> 6, lane = tid & 63;
  int l16 = lane & 15, q = lane >> 4;
  int g = q, mloc = l16;
  int tile = blockIdx.x * 4 + wave;
  int m0 = tile * 16;
  bool alive = m0 < M;
  int tileC = alive ? tile : 0;

  __shared__ float ldsT_s[4][16 * 68];
  float* myT = ldsT_s[wave];

  half8v a[4];
#pragma unroll
  for (int kc = 0; kc < 4; kc++)
    a[kc] = *(const half8v*)(aggp + (size_t)tileC * 2048 + (kc << 9) + lane * 8);

  float sv = *skipv;
  float alpha = 1.f / (1.f + __expf(-sv));
  float beta = 1.f - alpha;

  floatx4 acc1[8];
#pragma unroll
  for (int nt = 0; nt < 8; nt++) acc1[nt] = (floatx4){0.f, 0.f, 0.f, 0.f};
#pragma unroll
  for (int kc = 0; kc < 4; kc++) {
    half8v b[8];
#pragma unroll
    for (int nt = 0; nt < 8; nt++)
      b[nt] = *(const half8v*)(Wg1 + (size_t)nt * 2048 + (kc << 9) + lane * 8);
#pragma unroll
    for (int nt = 0; nt < 8; nt++)
      acc1[nt] = __builtin_amdgcn_mfma_f32_16x16x32_f16(a[kc], b[nt], acc1[nt], 0, 0, 0);
  }

#pragma unroll
  for (int p = 0; p < 2; p++) {
#pragma unroll
    for (int ntl = 0; ntl < 4; ntl++)
#pragma unroll
      for (int r = 0; r < 4; r++)
        myT[(q * 4 + r) * 68 + ntl * 16 + l16] = acc1[p * 4 + ntl][r];
    LWAIT;
    if (alive) {
      int row = m0 + mloc;
#pragma unroll
      for (int kc2 = 0; kc2 < 2; kc2++) {
        const float* rp = myT + mloc * 68 + kc2 * 32 + g * 8;
        floatx4 v0 = *(const floatx4*)rp;
        floatx4 v1 = *(const floatx4*)(rp + 4);
        float vals[8] = {v0[0], v0[1], v0[2], v0[3], v1[0], v1[1], v1[2], v1[3]};
        int col0 = p * 64 + kc2 * 32 + g * 8;
        size_t pbase = ((size_t)(tile * 4 + (col0 >> 5)) << 9) + (size_t)lane * 8;
        half8v hv = *(const half8v*)(hbuf + pbase);
#pragma unroll
        for (int j = 0; j < 8; j++) vals[j] = alpha * vals[j] + beta * (float)hv[j];
        *(float4*)&hfinal[(size_t)row * 128 + col0] =
            make_float4(vals[0], vals[1], vals[2], vals[3]);
        *(float4*)&hfinal[(size_t)row * 128 + col0 + 4] =
            make_float4(vals[4], vals[5], vals[6], vals[7]);
        half8v h8;
#pragma unroll
        for (int j = 0; j < 8; j++) h8[j] = (_Float16)vals[j];
        *(half8v*)&hrow[(size_t)row * 128 + col0] = h8;
      }
    }
    LWAIT;
  }
}

// ---------------- fused predictor: Z=h[a]*h[b] -> W1+leaky -> W2+leaky -> dot W3
__global__ __launch_bounds__(256) void pred_fused(
    const _Float16* __restrict__ hrow,
    const int* __restrict__ ps, const int* __restrict__ pd,
    const int* __restrict__ ns, const int* __restrict__ nd,
    const _Float16* __restrict__ W1f, const float* __restrict__ b1,
    const _Float16* __restrict__ W2f, const float* __restrict__ b2,
    const float* __restrict__ W3, const float* __restrict__ b3,
    float* __restrict__ outd, int M) {
  int tid = threadIdx.x;
  int wave = tid >> 6, lane = tid & 63;
  int l16 = lane & 15, q = lane >> 4;
  int g = q, mloc = l16;
  int tile = blockIdx.x * 4 + wave;
  int m0 = tile * 16;
  bool alive = m0 < M;

  __shared__ _Float16 t1_s[4][1024];
  __shared__ float ldsT_s[4][16 * 68];
  _Float16* t1tile = t1_s[wave];
  float* myT = ldsT_s[wave];

  int gr = min(m0 + l16, M - 1);
  bool pos = gr < N_PAIRS;
  int idx = pos ? gr : gr - N_PAIRS;
  int pa = pos ? ps[idx] : ns[idx];
  int pb = pos ? pd[idx] : nd[idx];

  half8v a[4];
#pragma unroll
  for (int kc = 0; kc < 4; kc++) {
    int kbase = kc * 32 + q * 8;
    half8v ha = *(const half8v*)(hrow + (size_t)pa * 128 + kbase);
    half8v hb = *(const half8v*)(hrow + (size_t)pb * 128 + kbase);
    a[kc] = ha * hb;
  }

  floatx4 acc1[4];
#pragma unroll
  for (int nt = 0; nt < 4; nt++) acc1[nt] = (floatx4){0.f, 0.f, 0.f, 0.f};
#pragma unroll
  for (int kc = 0; kc < 4; kc++) {
    half8v b[4];
#pragma unroll
    for (int nt = 0; nt < 4; nt++)
      b[nt] = *(const half8v*)(W1f + (size_t)nt * 2048 + (kc << 9) + lane * 8);
#pragma unroll
    for (int nt = 0; nt < 4; nt++)
      acc1[nt] = __builtin_amdgcn_mfma_f32_16x16x32_f16(a[kc], b[nt], acc1[nt], 0, 0, 0);
  }

  // epilogue1: bias+leaky -> per-wave T1 fragments (16 rows x 64 k)
#pragma unroll
  for (int ntl = 0; ntl < 4; ntl++)
#pragma unroll
    for (int r = 0; r < 4; r++)
      myT[(q * 4 + r) * 68 + ntl * 16 + l16] = acc1[ntl][r];
  LWAIT;
#pragma unroll
  for (int kc2 = 0; kc2 < 2; kc2++) {
    const float* rp = myT + mloc * 68 + kc2 * 32 + g * 8;
    floatx4 v0 = *(const floatx4*)rp;
    floatx4 v1 = *(const floatx4*)(rp + 4);
    float vals[8] = {v0[0], v0[1], v0[2], v0[3], v1[0], v1[1], v1[2], v1[3]};
    int col0 = kc2 * 32 + g * 8;
    float4 bb0 = *(const float4*)&b1[col0];
    float4 bb1 = *(const float4*)&b1[col0 + 4];
    float bbv[8] = {bb0.x, bb0.y, bb0.z, bb0.w, bb1.x, bb1.y, bb1.z, bb1.w};
    half8v h8;
#pragma unroll
    for (int j = 0; j < 8; j++) {
      float v = vals[j] + bbv[j];
      v = v > 0.f ? v : 0.2f * v;
      h8[j] = (_Float16)v;
    }
    *(half8v*)(t1tile + ((kc2 << 9) + (g << 7) + (mloc << 3))) = h8;
  }
  LWAIT;

  // GEMM2: T1 @ W2 (K=64, N=32) + leaky + dot W3
  floatx4 acc2[2];
#pragma unroll
  for (int nt = 0; nt < 2; nt++) acc2[nt] = (floatx4){0.f, 0.f, 0.f, 0.f};
#pragma unroll
  for (int kc = 0; kc < 2; kc++) {
    half8v af = *(const half8v*)(t1tile + ((kc << 9) + lane * 8));
    half8v b[2];
#pragma unroll
    for (int nt = 0; nt < 2; nt++)
      b[nt] = *(const half8v*)(W2f + (size_t)nt * 1024 + (kc << 9) + lane * 8);
#pragma unroll
    for (int nt = 0; nt < 2; nt++)
      acc2[nt] = __builtin_amdgcn_mfma_f32_16x16x32_f16(af, b[nt], acc2[nt], 0, 0, 0);
  }

  float bw[2], wv[2];
#pragma unroll
  for (int nt = 0; nt < 2; nt++) {
    int col = nt * 16 + l16;
    bw[nt] = b2[col];
    wv[nt] = W3[col];
  }
  float b3v = b3[0];
#pragma unroll
  for (int r = 0; r < 4; r++) {
    float partial = 0.f;
#pragma unroll
    for (int nt = 0; nt < 2; nt++) {
      float v = acc2[nt][r] + bw[nt];
      v = v > 0.f ? v : 0.2f * v;
      partial += v * wv[nt];
    }
    partial += __shfl_xor(partial, 1);
    partial += __shfl_xor(partial, 2);
    partial += __shfl_xor(partial, 4);
    partial += __shfl_xor(partial, 8);
    int row = m0 + q * 4 + r;
    if (l16 == 0 && alive && row < M) outd[row] = partial + b3v;
  }
}

// ---------------- per-destination online-softmax aggregation
// R2's measured-best variant: one node per half-wave, 8-edge chunks,
// depth-3 rotating pipeline (63.6us measured).
__global__ __launch_bounds__(256) void edge_agg_kernel(
    const _Float16* __restrict__ kwmv, const _Float16* __restrict__ qbuf,
    const int* __restrict__ poffs, const int2* __restrict__ eld,
    const int* __restrict__ perm,
    _Float16* __restrict__ agg, int n) {
  int hw = (blockIdx.x * 256 + threadIdx.x) >> 5;  // half-wave stream id
  int stride = gridDim.x << 3;                     // half-waves in grid
  int c4 = threadIdx.x & 31;
  int ch = c4 << 2;
  for (int gw = hw; gw < n; gw += stride) {
    int node = perm[gw];
    half4v qv = *(const half4v*)&qbuf[(size_t)node * 128 + ch];
    half2v q01 = {qv[0], qv[1]}, q23 = {qv[2], qv[3]};
    float m = -1e30f, s = 0.f;
    float a0 = 0.f, a1 = 0.f, a2 = 0.f, a3 = 0.f;
    int beg = poffs[node], end = poffs[node + 1];
    if (beg < end) {
      int2 e0[8], e1[8], e2[8];
      half8v g0[8], g1[8];
      // prologue: load chunk0 meta, issue chunk0 gathers, prefetch chunk1 meta
#pragma unroll
      for (int i = 0; i < 8; i++) e0[i] = eld[beg + i];
#pragma unroll
      for (int i = 0; i < 8; i++)
        g0[i] = *(const half8v*)&kwmv[(size_t)max(e0[i].x, 0) * 256 + (size_t)c4 * 8];
#pragma unroll
      for (int i = 0; i < 8; i++) e1[i] = eld[beg + 8 + i];
      int j = beg;
      for (; j + 8 < end; j += 8) {
        // issue next chunk's gathers (waits only on e1 arrival; g0 stays in flight)
#pragma unroll
        for (int i = 0; i < 8; i++)
          g1[i] = *(const half8v*)&kwmv[(size_t)max(e1[i].x, 0) * 256 + (size_t)c4 * 8];
        // prefetch meta two chunks ahead (may read past `end`; region is allocated)
#pragma unroll
        for (int i = 0; i < 8; i++) e2[i] = eld[j + 16 + i];
        // ---- compute on (e0, g0) — overlaps g1 + e2 flight
        float p[8];
#pragma unroll
        for (int i = 0; i < 8; i++) {
          half2v k01 = {g0[i][0], g0[i][1]}, k23 = {g0[i][2], g0[i][3]};
          float d = __builtin_amdgcn_fdot2(
              k01, q01, __builtin_amdgcn_fdot2(k23, q23, 0.f, false), false);
          d += __shfl_xor(d, 1);
          d += __shfl_xor(d, 2);
          p[i] = (e0[i].x >= 0) ? d : -1e30f;
        }
        float nm = m;
#pragma unroll
        for (int i = 0; i < 8; i++) nm = fmaxf(nm, p[i]);
        float sc = __expf(m - nm);
        float t[8];
        float ssum = 0.f;
#pragma unroll
        for (int i = 0; i < 8; i++) {
          t[i] = __expf(p[i] - nm);
          ssum += t[i];
        }
        s = s * sc + ssum;
        a0 *= sc; a1 *= sc; a2 *= sc; a3 *= sc;
#pragma unroll
        for (int i = 0; i < 8; i++) {
          float w = (e0[i].x >= 0) ? __int_as_float(e0[i].y) : 0.f;
          float f = t[i] * w;
          a0 += f * (float)g0[i][4];
          a1 += f * (float)g0[i][5];
          a2 += f * (float)g0[i][6];
          a3 += f * (float)g0[i][7];
        }
        m = nm;
        // rotate pipeline registers (static indices; compiler renames)
#pragma unroll
        for (int i = 0; i < 8; i++) {
          e0[i] = e1[i];
          e1[i] = e2[i];
          g0[i] = g1[i];
        }
      }
      // epilogue: last chunk
      {
        float p[8];
#pragma unroll
        for (int i = 0; i < 8; i++) {
          half2v k01 = {g0[i][0], g0[i][1]}, k23 = {g0[i][2], g0[i][3]};
          float d = __builtin_amdgcn_fdot2(
              k01, q01, __builtin_amdgcn_fdot2(k23, q23, 0.f, false), false);
          d += __shfl_xor(d, 1);
          d += __shfl_xor(d, 2);
          p[i] = (e0[i].x >= 0) ? d : -1e30f;
        }
        float nm = m;
#pragma unroll
        for (int i = 0; i < 8; i++) nm = fmaxf(nm, p[i]);
        float sc = __expf(m - nm);
        float t[8];
        float ssum = 0.f;
#pragma unroll
        for (int i = 0; i < 8; i++) {
          t[i] = __expf(p[i] - nm);
          ssum += t[i];
        }
        s = s * sc + ssum;
        a0 *= sc; a1 *= sc; a2 *= sc; a3 *= sc;
#pragma unroll
        for (int i = 0; i < 8; i++) {
          float w = (e0[i].x >= 0) ? __int_as_float(e0[i].y) : 0.f;
          float f = t[i] * w;
          a0 += f * (float)g0[i][4];
          a1 += f * (float)g0[i][5];
          a2 += f * (float)g0[i][6];
          a3 += f * (float)g0[i][7];
        }
      }
    }
    float inv = (s > 0.f) ? 1.f / s : 0.f;
    half4v out4;
    out4[0] = (_Float16)(a0 * inv);
    out4[1] = (_Float16)(a1 * inv);
    out4[2] = (_Float16)(a2 * inv);
    out4[3] = (_Float16)(a3 * inv);
    *(half4v*)&agg[packA(node, ch, 128)] = out4;
  }
}

extern "C" void kernel_launch(void* const* d_in, const int* in_sizes, int n_in,
                              void* d_out, int out_size, void* d_ws, size_t ws_size,
                              hipStream_t stream) {
  const float* x        = (const float*)d_in[0];
  const int*   edge_src = (const int*)d_in[1];
  const int*   edge_dst = (const int*)d_in[2];
  const float* edge_w   = (const float*)d_in[3];
  const int*   pos_src  = (const int*)d_in[4];
  const int*   pos_dst  = (const int*)d_in[5];
  const int*   neg_src  = (const int*)d_in[6];
  const int*   neg_dst  = (const int*)d_in[7];
  const float* W_in     = (const float*)d_in[8];
  const float* b_in     = (const float*)d_in[9];
  const float* Wk       = (const float*)d_in[10];
  const float* Wq       = (const float*)d_in[11];
  const float* Wv       = (const float*)d_in[12];
  const float* att_w    = (const float*)d_in[13];
  const float* msg_w    = (const float*)d_in[14];
  const float* pri      = (const float*)d_in[15];
  const float* Wa       = (const float*)d_in[16];
  const float* skip     = (const float*)d_in[17];
  const float* W1       = (const float*)d_in[18];
  const float* b1       = (const float*)d_in[19];
  const float* W2       = (const float*)d_in[20];
  const float* b2       = (const float*)d_in[21];
  const float* W3       = (const float*)d_in[22];
  const float* b3       = (const float*)d_in[23];
  float* out = (float*)d_out;

  // ---- workspace layout (bytes), ~91 MB
  char* W = (char*)d_ws;
  _Float16*  qbuf   = (_Float16*)(W + 0);          // 12,800,000
  _Float16*  kwmv   = (_Float16*)(W + 12800000);   // 25,600,000
  _Float16*  hbuf   = (_Float16*)(W + 38400000);   // 12,800,000 (packed h)
  _Float16*  agg    = (_Float16*)(W + 51200000);   // 12,800,000
  _Float16*  Wint   = (_Float16*)(W + 64000000);   // 32,768
  _Float16*  Wcat   = (_Float16*)(W + 64032768);   // 294,912
  _Float16*  Waf    = (_Float16*)(W + 64327680);   // 98,304
  _Float16*  W1f    = (_Float16*)(W + 64425984);   // 16,384
  _Float16*  W2f    = (_Float16*)(W + 64442368);   // 8,192
  int2*      eld    = (int2*)(W + 64450560);       // 12,800,000 (padded-8 edges)
  int*       deg    = (int*)(W + 77250560);        // 200,000
  int*       poffs  = (int*)(W + 77450560);        // 200,016
  int*       cursor = (int*)(W + 77650576);        // 200,000
  int*       perm   = (int*)(W + 77850576);        // 200,000
  int*       bsum   = (int*)(W + 78050576);        // 1,024
  int*       boff   = (int*)(W + 78051600);        // 1,024
  int*       bh     = (int*)(W + 78052624);        // 1,024
  int*       bcur   = (int*)(W + 78053648);        // 1,024
  _Float16*  hrow   = (_Float16*)(W + 78054912);   // 12,800,000 (fp16 row-major hfinal)
  float* hfinal = out + 2 * N_PAIRS;

  hipMemsetAsync(deg, 0, N_NODES * sizeof(int), stream);
  hipMemsetAsync(bh, 0, 1024, stream);
  // sentinel: src=-1. pad-8 worst case: E + 7*N slots = 9.2MB
  hipMemsetAsync(eld, 0xFF, 9600000, stream);

  wprep_kernel<<<880, 256, 0, stream>>>(W_in, Wk, Wq, Wv, att_w, msg_w, pri, Wa, W1, W2,
                                        Wint, Wcat, Waf, W1f, W2f);
  hist_kernel<<<(N_EDGES + 255) / 256, 256, 0, stream>>>(edge_dst, deg, N_EDGES);
  scanA_kernel<<<196, 256, 0, stream>>>(deg, poffs, bsum, N_NODES);
  scanB_kernel<<<1, 256, 0, stream>>>(bsum, boff, poffs, 196, N_NODES);
  scanC_kernel<<<196, 256, 0, stream>>>(poffs, boff, cursor, N_NODES);
  scatter_kernel<<<(N_EDGES + 255) / 256, 256, 0, stream>>>(
      edge_src, edge_dst, edge_w, cursor, eld, N_EDGES);
  bhist_kernel<<<196, 256, 0, stream>>>(deg, bh, N_NODES);
  bscan_kernel<<<1, 256, 0, stream>>>(bh, bcur);
  bscatter_kernel<<<196, 256, 0, stream>>>(deg, bcur, perm, N_NODES);

  // layer 0: x -> h_in (relu proj) -> kqv0
  fused_layer<1><<<782, 256, 0, stream>>>(x, nullptr, Wint, b_in, nullptr, hbuf,
                                          Wcat, kwmv, qbuf, N_NODES);
  edge_agg_kernel<<<2048, 256, 0, stream>>>(kwmv, qbuf, poffs, eld, perm, agg, N_NODES);
  // layer 1: agg0 -> h0 (skip-mix+relu) -> kqv1
  fused_layer<0><<<782, 256, 0, stream>>>(nullptr, agg, Waf, nullptr, skip + 0, hbuf,
                                          Wcat + 49152, kwmv, qbuf, N_NODES);
  edge_agg_kernel<<<2048, 256, 0, stream>>>(kwmv, qbuf, poffs, eld, perm, agg, N_NODES);
  // layer 2: agg1 -> h1 (skip-mix+relu) -> kqv2
  fused_layer<0><<<782, 256, 0, stream>>>(nullptr, agg, Waf + 16384, nullptr, skip + 1,
                                          hbuf, Wcat + 98304, kwmv, qbuf, N_NODES);
  edge_agg_kernel<<<2048, 256, 0, stream>>>(kwmv, qbuf, poffs, eld, perm, agg, N_NODES);
  // final: agg2 -> hfinal (skip-mix, no relu) + hrow fp16
  gemm_last<<<782, 256, 0, stream>>>(agg, Waf + 32768, skip + 2, hbuf,
                                     hfinal, hrow, N_NODES);
  // predictor (fully fused)
  pred_fused<<<3125, 256, 0, stream>>>(hrow, pos_src, pos_dst, neg_src, neg_dst,
                                       W1f, b1, W2f, b2, W3, b3, out, 2 * N_PAIRS);
}

// Round 7
// 538.578 us; speedup vs baseline: 1.7255x; 1.0198x over previous
//
#include <hip/hip_runtime.h>
#include <cstddef>

#define N_NODES 50000
#define N_EDGES 800000
#define N_PAIRS 100000

typedef float floatx4 __attribute__((ext_vector_type(4)));
typedef _Float16 half2v __attribute__((ext_vector_type(2)));
typedef _Float16 half4v __attribute__((ext_vector_type(4)));
typedef _Float16 half8v __attribute__((ext_vector_type(8)));

// intra-wave LDS fence (validated R6): per-wave LDS + in-order DS ops means
// lgkmcnt(0) + sched_barrier replaces __syncthreads (no vmcnt drain).
#define LWAIT { asm volatile("s_waitcnt lgkmcnt(0)" ::: "memory"); __builtin_amdgcn_sched_barrier(0); }

// packed MFMA A/B-fragment layout: [tile16][kchunk32][lane][8] (fp16)
__device__ inline size_t packA(int m, int k, int K) {
  return ((size_t)((m >> 4) * (K >> 5) + (k >> 5)) << 9) +
         ((((unsigned)k >> 3) & 3) << 7) + ((m & 15) << 3) + (k & 7);
}

// ---------------- weight prep (fold + transpose + pack, fp16)
__device__ inline float fold_val(int l, int r, int j, const float* Wk, const float* Wq,
                                 const float* Wv, const float* att, const float* msg,
                                 const float* pri) {
  if (j >= 128 && j < 256) return Wq[(l * 128 + r) * 128 + (j - 128)];
  int jj = j & 127, hh = jj >> 4, e = jj & 15;
  const float* W = (j < 128) ? Wk : Wv;
  const float* T = (j < 128) ? att : msg;
  float s = 0.f;
#pragma unroll
  for (int d = 0; d < 16; d++)
    s += W[(l * 128 + r) * 128 + hh * 16 + d] * T[((l * 8 + hh) * 16 + d) * 16 + e];
  if (j < 128) s *= pri[l * 8 + hh] * 0.25f;
  return s;
}

__global__ void wprep_kernel(const float* __restrict__ W_in, const float* __restrict__ Wk,
                             const float* __restrict__ Wq, const float* __restrict__ Wv,
                             const float* __restrict__ att, const float* __restrict__ msg,
                             const float* __restrict__ pri, const float* __restrict__ Wa,
                             const float* __restrict__ W1, const float* __restrict__ W2,
                             _Float16* Wint, _Float16* Wcat, _Float16* Waf,
                             _Float16* W1f, _Float16* W2f) {
  int gid = blockIdx.x * 256 + threadIdx.x;
  float v;
  _Float16* dt;
  size_t o;
  if (gid < 16384) {
    int n = gid >> 7, k = gid & 127;
    v = W_in[k * 128 + n];
    dt = Wint; o = packA(n, k, 128);
  } else if (gid < 163840) {
    int t = gid - 16384;
    int l = t / 49152, u = t - l * 49152;
    int n = u >> 7, k = u & 127;
    v = fold_val(l, k, n, Wk, Wq, Wv, att, msg, pri);
    dt = Wcat + (size_t)l * 49152;
    o = packA(n, k, 128);
  } else if (gid < 212992) {
    int t = gid - 163840;
    int l = t / 16384, u = t & 16383;
    int n = u >> 7, k = u & 127;
    v = Wa[(size_t)l * 16384 + k * 128 + n];
    dt = Waf + (size_t)l * 16384;
    o = packA(n, k, 128);
  } else if (gid < 221184) {
    int u = gid - 212992;
    int n = u >> 7, k = u & 127;
    v = W1[k * 64 + n];
    dt = W1f; o = packA(n, k, 128);
  } else if (gid < 225280) {
    int u = gid - 221184;
    int n = u >> 6, k = u & 63;
    v = (n < 32) ? W2[k * 32 + n] : 0.f;
    dt = W2f; o = packA(n, k, 64);
  } else {
    return;
  }
  dt[o] = (_Float16)v;
}

// ---------------- CSR build (padded to multiple of 8 per node)
__global__ void hist_kernel(const int* __restrict__ dst, int* __restrict__ deg, int E) {
  int g = blockIdx.x * blockDim.x + threadIdx.x;
  if (g < E) atomicAdd(&deg[dst[g]], 1);
}

__global__ void scanA_kernel(const int* __restrict__ deg, int* __restrict__ offs,
                             int* __restrict__ bsum, int n) {
  __shared__ int sm[256];
  int t = threadIdx.x;
  int i = blockIdx.x * 256 + t;
  int v = (i < n) ? ((deg[i] + 7) & ~7) : 0;
  sm[t] = v;
  __syncthreads();
  for (int off = 1; off < 256; off <<= 1) {
    int u = (t >= off) ? sm[t - off] : 0;
    __syncthreads();
    sm[t] += u;
    __syncthreads();
  }
  if (i < n) offs[i] = sm[t] - v;
  if (t == 255) bsum[blockIdx.x] = sm[255];
}

__global__ void scanB_kernel(const int* __restrict__ bsum, int* __restrict__ boff,
                             int* __restrict__ offs, int nb, int n) {
  __shared__ int sm[256];
  int t = threadIdx.x;
  int v = (t < nb) ? bsum[t] : 0;
  sm[t] = v;
  __syncthreads();
  for (int off = 1; off < 256; off <<= 1) {
    int u = (t >= off) ? sm[t - off] : 0;
    __syncthreads();
    sm[t] += u;
    __syncthreads();
  }
  boff[t] = sm[t] - v;
  if (t == nb - 1) offs[n] = sm[t];
}

__global__ void scanC_kernel(int* __restrict__ offs, const int* __restrict__ boff,
                             int* __restrict__ cursor, int n) {
  int i = blockIdx.x * 256 + threadIdx.x;
  if (i < n) {
    int o = offs[i] + boff[blockIdx.x];
    offs[i] = o;
    cursor[i] = o;
  }
}

__global__ void scatter_kernel(const int* __restrict__ src, const int* __restrict__ dst,
                               const float* __restrict__ w, int* __restrict__ cursor,
                               int2* __restrict__ eld, int E) {
  int g = blockIdx.x * blockDim.x + threadIdx.x;
  if (g < E) {
    int d = dst[g];
    int p = atomicAdd(&cursor[d], 1);
    eld[p] = make_int2(src[g], __float_as_int(w[g]));
  }
}

// ---------------- degree-descending node permutation (counting sort, 256 buckets)
__global__ void bhist_kernel(const int* __restrict__ deg, int* __restrict__ bh, int n) {
  __shared__ int lh[256];
  int t = threadIdx.x;
  lh[t] = 0;
  __syncthreads();
  int i = blockIdx.x * 256 + t;
  if (i < n) atomicAdd(&lh[min(deg[i], 255)], 1);
  __syncthreads();
  if (lh[t]) atomicAdd(&bh[t], lh[t]);
}
__global__ void bscan_kernel(const int* __restrict__ bh, int* __restrict__ bcur) {
  __shared__ int sm[256];
  int t = threadIdx.x;
  int v = bh[255 - t];
  sm[t] = v;
  __syncthreads();
  for (int off = 1; off < 256; off <<= 1) {
    int u = (t >= off) ? sm[t - off] : 0;
    __syncthreads();
    sm[t] += u;
    __syncthreads();
  }
  bcur[255 - t] = sm[t] - v;
}
__global__ void bscatter_kernel(const int* __restrict__ deg, int* __restrict__ bcur,
                                int* __restrict__ perm, int n) {
  __shared__ int lh[256], lbase[256];
  int t = threadIdx.x;
  lh[t] = 0;
  __syncthreads();
  int i = blockIdx.x * 256 + t;
  int b = 0, local = 0;
  if (i < n) {
    b = min(deg[i], 255);
    local = atomicAdd(&lh[b], 1);
  }
  __syncthreads();
  int cnt = lh[t];
  lbase[t] = cnt ? atomicAdd(&bcur[t], cnt) : 0;
  __syncthreads();
  if (i < n) perm[lbase[b] + local] = i;
}

// ---------------- fused layer kernel: GEMM1 (h) -> LDS fragments -> GEMM2 (kqv)
// TWO adjacent 16-row tiles per wave: each loaded B fragment feeds 2 MFMA ->
// weight fetch + issue halves vs 1-tile. A-fragments loaded per-kc (bounded VGPR).
template <int FIRST>
__global__ __launch_bounds__(256) void fused_layer(
    const float* __restrict__ x, const _Float16* __restrict__ aggp,
    const _Float16* __restrict__ Wg1, const float* __restrict__ bias,
    const float* __restrict__ skipv, _Float16* __restrict__ hbuf,
    const _Float16* __restrict__ Wcat_l,
    _Float16* __restrict__ kwmv, _Float16* __restrict__ qbuf, int M) {
  int tid = threadIdx.x;
  int wave = tid >> 6, lane = tid & 63;
  int l16 = lane & 15, q = lane >> 4;
  int g = q, mloc = l16;
  int t0 = (blockIdx.x * 4 + wave) * 2;  // two adjacent tiles per wave

  __shared__ _Float16 htile_s[4][2][2048];
  __shared__ float ldsT_s[4][16 * 68];
  float* myT = ldsT_s[wave];

  float alpha = 1.f, beta = 0.f;
  if (!FIRST) {
    float sv = *skipv;
    alpha = 1.f / (1.f + __expf(-sv));
    beta = 1.f - alpha;
  }

  floatx4 acc[2][8];
#pragma unroll
  for (int t = 0; t < 2; t++)
#pragma unroll
    for (int nt = 0; nt < 8; nt++) acc[t][nt] = (floatx4){0.f, 0.f, 0.f, 0.f};

  // GEMM1: per-kc A loads (both tiles) + shared B fragments
#pragma unroll
  for (int kc = 0; kc < 4; kc++) {
    half8v a0, a1;
#pragma unroll
    for (int t = 0; t < 2; t++) {
      int tile = t0 + t;
      int tileC = (tile * 16 < M) ? tile : 0;
      half8v av;
      if (FIRST) {
        int row = min(tile * 16 + l16, M - 1);
        const float* p = x + (size_t)row * 128 + kc * 32 + q * 8;
        float4 u0 = *(const float4*)p, u1 = *(const float4*)(p + 4);
        float f[8] = {u0.x, u0.y, u0.z, u0.w, u1.x, u1.y, u1.z, u1.w};
#pragma unroll
        for (int i = 0; i < 8; i++) av[i] = (_Float16)f[i];
      } else {
        av = *(const half8v*)(aggp + (size_t)tileC * 2048 + (kc << 9) + lane * 8);
      }
      if (t == 0) a0 = av; else a1 = av;
    }
#pragma unroll
    for (int nt = 0; nt < 8; nt++) {
      half8v b = *(const half8v*)(Wg1 + (size_t)nt * 2048 + (kc << 9) + lane * 8);
      acc[0][nt] = __builtin_amdgcn_mfma_f32_16x16x32_f16(a0, b, acc[0][nt], 0, 0, 0);
      acc[1][nt] = __builtin_amdgcn_mfma_f32_16x16x32_f16(a1, b, acc[1][nt], 0, 0, 0);
    }
  }

  // epilogue1 per tile: transpose via myT; emit packed hbuf + htile fragments
#pragma unroll
  for (int t = 0; t < 2; t++) {
    int tile = t0 + t;
    bool alive = tile * 16 < M;
    int tileC = alive ? tile : 0;
#pragma unroll
    for (int p = 0; p < 2; p++) {
#pragma unroll
      for (int ntl = 0; ntl < 4; ntl++)
#pragma unroll
        for (int r = 0; r < 4; r++)
          myT[(q * 4 + r) * 68 + ntl * 16 + l16] = acc[t][p * 4 + ntl][r];
      LWAIT;
#pragma unroll
      for (int kc2 = 0; kc2 < 2; kc2++) {
        const float* rp = myT + mloc * 68 + kc2 * 32 + g * 8;
        floatx4 v0 = *(const floatx4*)rp;
        floatx4 v1 = *(const floatx4*)(rp + 4);
        float vals[8] = {v0[0], v0[1], v0[2], v0[3], v1[0], v1[1], v1[2], v1[3]};
        int col0 = p * 64 + kc2 * 32 + g * 8;
        size_t pbaseL = ((size_t)(tileC * 4 + (col0 >> 5)) << 9) + (size_t)lane * 8;
        if (FIRST) {
          float4 bb0 = *(const float4*)&bias[col0];
          float4 bb1 = *(const float4*)&bias[col0 + 4];
          float bbv[8] = {bb0.x, bb0.y, bb0.z, bb0.w, bb1.x, bb1.y, bb1.z, bb1.w};
#pragma unroll
          for (int j = 0; j < 8; j++) vals[j] = fmaxf(vals[j] + bbv[j], 0.f);
        } else {
          half8v hv = *(const half8v*)(hbuf + pbaseL);
#pragma unroll
          for (int j = 0; j < 8; j++)
            vals[j] = fmaxf(alpha * vals[j] + beta * (float)hv[j], 0.f);
        }
        half8v h8;
#pragma unroll
        for (int j = 0; j < 8; j++) h8[j] = (_Float16)vals[j];
        *(half8v*)(&htile_s[wave][t][0] + (((p * 2 + kc2) << 9) + (g << 7) + (mloc << 3))) = h8;
        if (alive) *(half8v*)(hbuf + pbaseL) = h8;
      }
      LWAIT;  // myT reads done before next phase overwrites
    }
  }

  // GEMM2: kqv = h-tiles @ Wcat (384 cols, 6 chunks of 64); B shared by 2 tiles
  LWAIT;  // htile writes visible
  for (int c = 0; c < 6; c++) {
    floatx4 acc2[2][4];
#pragma unroll
    for (int t = 0; t < 2; t++)
#pragma unroll
      for (int nt = 0; nt < 4; nt++) acc2[t][nt] = (floatx4){0.f, 0.f, 0.f, 0.f};
#pragma unroll
    for (int kc = 0; kc < 4; kc++) {
      half8v af0 = *(const half8v*)(&htile_s[wave][0][0] + ((kc << 9) + lane * 8));
      half8v af1 = *(const half8v*)(&htile_s[wave][1][0] + ((kc << 9) + lane * 8));
#pragma unroll
      for (int nt = 0; nt < 4; nt++) {
        half8v b = *(const half8v*)(Wcat_l + (size_t)(c * 4 + nt) * 2048 + (kc << 9) + lane * 8);
        acc2[0][nt] = __builtin_amdgcn_mfma_f32_16x16x32_f16(af0, b, acc2[0][nt], 0, 0, 0);
        acc2[1][nt] = __builtin_amdgcn_mfma_f32_16x16x32_f16(af1, b, acc2[1][nt], 0, 0, 0);
      }
    }
#pragma unroll
    for (int t = 0; t < 2; t++) {
      int tile = t0 + t;
      bool alive = tile * 16 < M;
      int m0 = tile * 16;
#pragma unroll
      for (int ntl = 0; ntl < 4; ntl++)
#pragma unroll
        for (int r = 0; r < 4; r++)
          myT[(q * 4 + r) * 68 + ntl * 16 + l16] = acc2[t][ntl][r];
      LWAIT;
      if (alive) {
        int row = m0 + mloc;
#pragma unroll
        for (int kc2 = 0; kc2 < 2; kc2++) {
          const float* rp = myT + mloc * 68 + kc2 * 32 + g * 8;
          floatx4 v0 = *(const floatx4*)rp;
          floatx4 v1 = *(const floatx4*)(rp + 4);
          int col0 = c * 64 + kc2 * 32 + g * 8;
          int region = col0 >> 7;  // 0 kw, 1 q, 2 mv
          if (region == 1) {
            half8v h8;
#pragma unroll
            for (int j = 0; j < 4; j++) {
              h8[j] = (_Float16)v0[j];
              h8[j + 4] = (_Float16)v1[j];
            }
            *(half8v*)&qbuf[(size_t)row * 128 + (col0 - 128)] = h8;
          } else {
            int cc = col0 & 127;
            size_t base = (size_t)row * 256 + (size_t)(cc >> 2) * 8 + (region == 2 ? 4 : 0);
            half4v h0, h1;
#pragma unroll
            for (int j = 0; j < 4; j++) {
              h0[j] = (_Float16)v0[j];
              h1[j] = (_Float16)v1[j];
            }
            *(half4v*)&kwmv[base] = h0;
            *(half4v*)&kwmv[base + 8] = h1;
          }
        }
      }
      LWAIT;  // myT reads done before next t/c overwrites
    }
  }
}

// ---------------- last Wa GEMM: hfinal = mix(agg @ Wa2, hold) (no relu) + hrow fp16
// 2 tiles per wave (shared B fragments).
__global__ __launch_bounds__(256) void gemm_last(
    const _Float16* __restrict__ aggp, const _Float16* __restrict__ Wg1,
    const float* __restrict__ skipv, const _Float16* __restrict__ hbuf,
    float* __restrict__ hfinal, _Float16* __restrict__ hrow, int M) {
  int tid = threadIdx.x;
  int wave = tid >> 6, lane = tid & 63;
  int l16 = lane & 15, q = lane >> 4;
  int g = q, mloc = l16;
  int t0 = (blockIdx.x * 4 + wave) * 2;

  __shared__ float ldsT_s[4][16 * 68];
  float* myT = ldsT_s[wave];

  float sv = *skipv;
  float alpha = 1.f / (1.f + __expf(-sv));
  float beta = 1.f - alpha;

  floatx4 acc[2][8];
#pragma unroll
  for (int t = 0; t < 2; t++)
#pragma unroll
    for (int nt = 0; nt < 8; nt++) acc[t][nt] = (floatx4){0.f, 0.f, 0.f, 0.f};

#pragma unroll
  for (int kc = 0; kc < 4; kc++) {
    int tC0 = (t0 * 16 < M) ? t0 : 0;
    int tC1 = ((t0 + 1) * 16 < M) ? (t0 + 1) : 0;
    half8v a0 = *(const half8v*)(aggp + (size_t)tC0 * 2048 + (kc << 9) + lane * 8);
    half8v a1 = *(const half8v*)(aggp + (size_t)tC1 * 2048 + (kc << 9) + lane * 8);
#pragma unroll
    for (int nt = 0; nt < 8; nt++) {
      half8v b = *(const half8v*)(Wg1 + (size_t)nt * 2048 + (kc << 9) + lane * 8);
      acc[0][nt] = __builtin_amdgcn_mfma_f32_16x16x32_f16(a0, b, acc[0][nt], 0, 0, 0);
      acc[1][nt] = __builtin_amdgcn_mfma_f32_16x16x32_f16(a1, b, acc[1][nt], 0, 0, 0);
    }
  }

#pragma unroll
  for (int t = 0; t < 2; t++) {
    int tile = t0 + t;
    bool alive = tile * 16 < M;
    int m0 = tile * 16;
#pragma unroll
    for (int p = 0; p < 2; p++) {
#pragma unroll
      for (int ntl = 0; ntl < 4; ntl++)
#pragma unroll
        for (int r = 0; r < 4; r++)
          myT[(q * 4 + r) * 68 + ntl * 16 + l16] = acc[t][p * 4 + ntl][r];
      LWAIT;
      if (alive) {
        int row = m0 + mloc;
#pragma unroll
        for (int kc2 = 0; kc2 < 2; kc2++) {
          const float* rp = myT + mloc * 68 + kc2 * 32 + g * 8;
          floatx4 v0 = *(const floatx4*)rp;
          floatx4 v1 = *(const floatx4*)(rp + 4);
          float vals[8] = {v0[0], v0[1], v0[2], v0[3], v1[0], v1[1], v1[2], v1[3]};
          int col0 = p * 64 + kc2 * 32 + g * 8;
          size_t pbase = ((size_t)(tile * 4 + (col0 >> 5)) << 9) + (size_t)lane * 8;
          half8v hv = *(const half8v*)(hbuf + pbase);
#pragma unroll
          for (int j = 0; j < 8; j++) vals[j] = alpha * vals[j] + beta * (float)hv[j];
          *(float4*)&hfinal[(size_t)row * 128 + col0] =
              make_float4(vals[0], vals[1], vals[2], vals[3]);
          *(float4*)&hfinal[(size_t)row * 128 + col0 + 4] =
              make_float4(vals[4], vals[5], vals[6], vals[7]);
          half8v h8;
#pragma unroll
          for (int j = 0; j < 8; j++) h8[j] = (_Float16)vals[j];
          *(half8v*)&hrow[(size_t)row * 128 + col0] = h8;
        }
      }
      LWAIT;
    }
  }
}

// ---------------- fused predictor: Z=h[a]*h[b] -> W1+leaky -> W2+leaky -> dot W3
// 2 tiles per wave (shared W1f/W2f fragments).
__global__ __launch_bounds__(256) void pred_fused(
    const _Float16* __restrict__ hrow,
    const int* __restrict__ ps, const int* __restrict__ pd,
    const int* __restrict__ ns, const int* __restrict__ nd,
    const _Float16* __restrict__ W1f, const float* __restrict__ b1,
    const _Float16* __restrict__ W2f, const float* __restrict__ b2,
    const float* __restrict__ W3, const float* __restrict__ b3,
    float* __restrict__ outd, int M) {
  int tid = threadIdx.x;
  int wave = tid >> 6, lane = tid & 63;
  int l16 = lane & 15, q = lane >> 4;
  int g = q, mloc = l16;
  int t0 = (blockIdx.x * 4 + wave) * 2;

  __shared__ _Float16 t1_s[4][2][1024];
  __shared__ float ldsT_s[4][16 * 68];
  float* myT = ldsT_s[wave];

  int pa[2], pb[2];
#pragma unroll
  for (int t = 0; t < 2; t++) {
    int gr = min((t0 + t) * 16 + l16, M - 1);
    bool pos = gr < N_PAIRS;
    int idx = pos ? gr : gr - N_PAIRS;
    pa[t] = pos ? ps[idx] : ns[idx];
    pb[t] = pos ? pd[idx] : nd[idx];
  }

  floatx4 acc1[2][4];
#pragma unroll
  for (int t = 0; t < 2; t++)
#pragma unroll
    for (int nt = 0; nt < 4; nt++) acc1[t][nt] = (floatx4){0.f, 0.f, 0.f, 0.f};

#pragma unroll
  for (int kc = 0; kc < 4; kc++) {
    int kbase = kc * 32 + q * 8;
    half8v a0, a1;
#pragma unroll
    for (int t = 0; t < 2; t++) {
      half8v ha = *(const half8v*)(hrow + (size_t)pa[t] * 128 + kbase);
      half8v hb = *(const half8v*)(hrow + (size_t)pb[t] * 128 + kbase);
      half8v av = ha * hb;
      if (t == 0) a0 = av; else a1 = av;
    }
#pragma unroll
    for (int nt = 0; nt < 4; nt++) {
      half8v b = *(const half8v*)(W1f + (size_t)nt * 2048 + (kc << 9) + lane * 8);
      acc1[0][nt] = __builtin_amdgcn_mfma_f32_16x16x32_f16(a0, b, acc1[0][nt], 0, 0, 0);
      acc1[1][nt] = __builtin_amdgcn_mfma_f32_16x16x32_f16(a1, b, acc1[1][nt], 0, 0, 0);
    }
  }

  // epilogue1 per tile: bias+leaky -> T1 fragments (16 rows x 64 k)
#pragma unroll
  for (int t = 0; t < 2; t++) {
#pragma unroll
    for (int ntl = 0; ntl < 4; ntl++)
#pragma unroll
      for (int r = 0; r < 4; r++)
        myT[(q * 4 + r) * 68 + ntl * 16 + l16] = acc1[t][ntl][r];
    LWAIT;
#pragma unroll
    for (int kc2 = 0; kc2 < 2; kc2++) {
      const float* rp = myT + mloc * 68 + kc2 * 32 + g * 8;
      floatx4 v0 = *(const floatx4*)rp;
      floatx4 v1 = *(const floatx4*)(rp + 4);
      float vals[8] = {v0[0], v0[1], v0[2], v0[3], v1[0], v1[1], v1[2], v1[3]};
      int col0 = kc2 * 32 + g * 8;
      float4 bb0 = *(const float4*)&b1[col0];
      float4 bb1 = *(const float4*)&b1[col0 + 4];
      float bbv[8] = {bb0.x, bb0.y, bb0.z, bb0.w, bb1.x, bb1.y, bb1.z, bb1.w};
      half8v h8;
#pragma unroll
      for (int j = 0; j < 8; j++) {
        float v = vals[j] + bbv[j];
        v = v > 0.f ? v : 0.2f * v;
        h8[j] = (_Float16)v;
      }
      *(half8v*)(&t1_s[wave][t][0] + ((kc2 << 9) + (g << 7) + (mloc << 3))) = h8;
    }
    LWAIT;
  }

  // GEMM2: T1 @ W2 (K=64, N=32) + leaky + dot W3, B shared by 2 tiles
  floatx4 acc2[2][2];
#pragma unroll
  for (int t = 0; t < 2; t++)
#pragma unroll
    for (int nt = 0; nt < 2; nt++) acc2[t][nt] = (floatx4){0.f, 0.f, 0.f, 0.f};
#pragma unroll
  for (int kc = 0; kc < 2; kc++) {
    half8v af0 = *(const half8v*)(&t1_s[wave][0][0] + ((kc << 9) + lane * 8));
    half8v af1 = *(const half8v*)(&t1_s[wave][1][0] + ((kc << 9) + lane * 8));
#pragma unroll
    for (int nt = 0; nt < 2; nt++) {
      half8v b = *(const half8v*)(W2f + (size_t)nt * 1024 + (kc << 9) + lane * 8);
      acc2[0][nt] = __builtin_amdgcn_mfma_f32_16x16x32_f16(af0, b, acc2[0][nt], 0, 0, 0);
      acc2[1][nt] = __builtin_amdgcn_mfma_f32_16x16x32_f16(af1, b, acc2[1][nt], 0, 0, 0);
    }
  }

  float bw[2], wv[2];
#pragma unroll
  for (int nt = 0; nt < 2; nt++) {
    int col = nt * 16 + l16;
    bw[nt] = b2[col];
    wv[nt] = W3[col];
  }
  float b3v = b3[0];
#pragma unroll
  for (int t = 0; t < 2; t++) {
    int m0 = (t0 + t) * 16;
    bool alive = m0 < M;
#pragma unroll
    for (int r = 0; r < 4; r++) {
      float partial = 0.f;
#pragma unroll
      for (int nt = 0; nt < 2; nt++) {
        float v = acc2[t][nt][r] + bw[nt];
        v = v > 0.f ? v : 0.2f * v;
        partial += v * wv[nt];
      }
      partial += __shfl_xor(partial, 1);
      partial += __shfl_xor(partial, 2);
      partial += __shfl_xor(partial, 4);
      partial += __shfl_xor(partial, 8);
      int row = m0 + q * 4 + r;
      if (l16 == 0 && alive && row < M) outd[row] = partial + b3v;
    }
  }
}

// ---------------- per-destination online-softmax aggregation
// Measured-best variant (R2/R6): one node per half-wave, 8-edge chunks,
// depth-3 rotating pipeline. At the ~6 TB/s random-gather service wall.
__global__ __launch_bounds__(256) void edge_agg_kernel(
    const _Float16* __restrict__ kwmv, const _Float16* __restrict__ qbuf,
    const int* __restrict__ poffs, const int2* __restrict__ eld,
    const int* __restrict__ perm,
    _Float16* __restrict__ agg, int n) {
  int hw = (blockIdx.x * 256 + threadIdx.x) >> 5;  // half-wave stream id
  int stride = gridDim.x << 3;                     // half-waves in grid
  int c4 = threadIdx.x & 31;
  int ch = c4 << 2;
  for (int gw = hw; gw < n; gw += stride) {
    int node = perm[gw];
    half4v qv = *(const half4v*)&qbuf[(size_t)node * 128 + ch];
    half2v q01 = {qv[0], qv[1]}, q23 = {qv[2], qv[3]};
    float m = -1e30f, s = 0.f;
    float a0 = 0.f, a1 = 0.f, a2 = 0.f, a3 = 0.f;
    int beg = poffs[node], end = poffs[node + 1];
    if (beg < end) {
      int2 e0[8], e1[8], e2[8];
      half8v g0[8], g1[8];
#pragma unroll
      for (int i = 0; i < 8; i++) e0[i] = eld[beg + i];
#pragma unroll
      for (int i = 0; i < 8; i++)
        g0[i] = *(const half8v*)&kwmv[(size_t)max(e0[i].x, 0) * 256 + (size_t)c4 * 8];
#pragma unroll
      for (int i = 0; i < 8; i++) e1[i] = eld[beg + 8 + i];
      int j = beg;
      for (; j + 8 < end; j += 8) {
#pragma unroll
        for (int i = 0; i < 8; i++)
          g1[i] = *(const half8v*)&kwmv[(size_t)max(e1[i].x, 0) * 256 + (size_t)c4 * 8];
#pragma unroll
        for (int i = 0; i < 8; i++) e2[i] = eld[j + 16 + i];
        float p[8];
#pragma unroll
        for (int i = 0; i < 8; i++) {
          half2v k01 = {g0[i][0], g0[i][1]}, k23 = {g0[i][2], g0[i][3]};
          float d = __builtin_amdgcn_fdot2(
              k01, q01, __builtin_amdgcn_fdot2(k23, q23, 0.f, false), false);
          d += __shfl_xor(d, 1);
          d += __shfl_xor(d, 2);
          p[i] = (e0[i].x >= 0) ? d : -1e30f;
        }
        float nm = m;
#pragma unroll
        for (int i = 0; i < 8; i++) nm = fmaxf(nm, p[i]);
        float sc = __expf(m - nm);
        float t[8];
        float ssum = 0.f;
#pragma unroll
        for (int i = 0; i < 8; i++) {
          t[i] = __expf(p[i] - nm);
          ssum += t[i];
        }
        s = s * sc + ssum;
        a0 *= sc; a1 *= sc; a2 *= sc; a3 *= sc;
#pragma unroll
        for (int i = 0; i < 8; i++) {
          float w = (e0[i].x >= 0) ? __int_as_float(e0[i].y) : 0.f;
          float f = t[i] * w;
          a0 += f * (float)g0[i][4];
          a1 += f * (float)g0[i][5];
          a2 += f * (float)g0[i][6];
          a3 += f * (float)g0[i][7];
        }
        m = nm;
#pragma unroll
        for (int i = 0; i < 8; i++) {
          e0[i] = e1[i];
          e1[i] = e2[i];
          g0[i] = g1[i];
        }
      }
      {
        float p[8];
#pragma unroll
        for (int i = 0; i < 8; i++) {
          half2v k01 = {g0[i][0], g0[i][1]}, k23 = {g0[i][2], g0[i][3]};
          float d = __builtin_amdgcn_fdot2(
              k01, q01, __builtin_amdgcn_fdot2(k23, q23, 0.f, false), false);
          d += __shfl_xor(d, 1);
          d += __shfl_xor(d, 2);
          p[i] = (e0[i].x >= 0) ? d : -1e30f;
        }
        float nm = m;
#pragma unroll
        for (int i = 0; i < 8; i++) nm = fmaxf(nm, p[i]);
        float sc = __expf(m - nm);
        float t[8];
        float ssum = 0.f;
#pragma unroll
        for (int i = 0; i < 8; i++) {
          t[i] = __expf(p[i] - nm);
          ssum += t[i];
        }
        s = s * sc + ssum;
        a0 *= sc; a1 *= sc; a2 *= sc; a3 *= sc;
#pragma unroll
        for (int i = 0; i < 8; i++) {
          float w = (e0[i].x >= 0) ? __int_as_float(e0[i].y) : 0.f;
          float f = t[i] * w;
          a0 += f * (float)g0[i][4];
          a1 += f * (float)g0[i][5];
          a2 += f * (float)g0[i][6];
          a3 += f * (float)g0[i][7];
        }
      }
    }
    float inv = (s > 0.f) ? 1.f / s : 0.f;
    half4v out4;
    out4[0] = (_Float16)(a0 * inv);
    out4[1] = (_Float16)(a1 * inv);
    out4[2] = (_Float16)(a2 * inv);
    out4[3] = (_Float16)(a3 * inv);
    *(half4v*)&agg[packA(node, ch, 128)] = out4;
  }
}

extern "C" void kernel_launch(void* const* d_in, const int* in_sizes, int n_in,
                              void* d_out, int out_size, void* d_ws, size_t ws_size,
                              hipStream_t stream) {
  const float* x        = (const float*)d_in[0];
  const int*   edge_src = (const int*)d_in[1];
  const int*   edge_dst = (const int*)d_in[2];
  const float* edge_w   = (const float*)d_in[3];
  const int*   pos_src  = (const int*)d_in[4];
  const int*   pos_dst  = (const int*)d_in[5];
  const int*   neg_src  = (const int*)d_in[6];
  const int*   neg_dst  = (const int*)d_in[7];
  const float* W_in     = (const float*)d_in[8];
  const float* b_in     = (const float*)d_in[9];
  const float* Wk       = (const float*)d_in[10];
  const float* Wq       = (const float*)d_in[11];
  const float* Wv       = (const float*)d_in[12];
  const float* att_w    = (const float*)d_in[13];
  const float* msg_w    = (const float*)d_in[14];
  const float* pri      = (const float*)d_in[15];
  const float* Wa       = (const float*)d_in[16];
  const float* skip     = (const float*)d_in[17];
  const float* W1       = (const float*)d_in[18];
  const float* b1       = (const float*)d_in[19];
  const float* W2       = (const float*)d_in[20];
  const float* b2       = (const float*)d_in[21];
  const float* W3       = (const float*)d_in[22];
  const float* b3       = (const float*)d_in[23];
  float* out = (float*)d_out;

  // ---- workspace layout (bytes), ~91 MB
  char* W = (char*)d_ws;
  _Float16*  qbuf   = (_Float16*)(W + 0);          // 12,800,000
  _Float16*  kwmv   = (_Float16*)(W + 12800000);   // 25,600,000
  _Float16*  hbuf   = (_Float16*)(W + 38400000);   // 12,800,000 (packed h)
  _Float16*  agg    = (_Float16*)(W + 51200000);   // 12,800,000
  _Float16*  Wint   = (_Float16*)(W + 64000000);   // 32,768
  _Float16*  Wcat   = (_Float16*)(W + 64032768);   // 294,912
  _Float16*  Waf    = (_Float16*)(W + 64327680);   // 98,304
  _Float16*  W1f    = (_Float16*)(W + 64425984);   // 16,384
  _Float16*  W2f    = (_Float16*)(W + 64442368);   // 8,192
  int2*      eld    = (int2*)(W + 64450560);       // 12,800,000 (padded-8 edges)
  int*       deg    = (int*)(W + 77250560);        // 200,000
  int*       poffs  = (int*)(W + 77450560);        // 200,016
  int*       cursor = (int*)(W + 77650576);        // 200,000
  int*       perm   = (int*)(W + 77850576);        // 200,000
  int*       bsum   = (int*)(W + 78050576);        // 1,024
  int*       boff   = (int*)(W + 78051600);        // 1,024
  int*       bh     = (int*)(W + 78052624);        // 1,024
  int*       bcur   = (int*)(W + 78053648);        // 1,024
  _Float16*  hrow   = (_Float16*)(W + 78054912);   // 12,800,000 (fp16 row-major hfinal)
  float* hfinal = out + 2 * N_PAIRS;

  hipMemsetAsync(deg, 0, N_NODES * sizeof(int), stream);
  hipMemsetAsync(bh, 0, 1024, stream);
  // sentinel: src=-1. pad-8 worst case: E + 7*N slots = 9.2MB
  hipMemsetAsync(eld, 0xFF, 9600000, stream);

  wprep_kernel<<<880, 256, 0, stream>>>(W_in, Wk, Wq, Wv, att_w, msg_w, pri, Wa, W1, W2,
                                        Wint, Wcat, Waf, W1f, W2f);
  hist_kernel<<<(N_EDGES + 255) / 256, 256, 0, stream>>>(edge_dst, deg, N_EDGES);
  scanA_kernel<<<196, 256, 0, stream>>>(deg, poffs, bsum, N_NODES);
  scanB_kernel<<<1, 256, 0, stream>>>(bsum, boff, poffs, 196, N_NODES);
  scanC_kernel<<<196, 256, 0, stream>>>(poffs, boff, cursor, N_NODES);
  scatter_kernel<<<(N_EDGES + 255) / 256, 256, 0, stream>>>(
      edge_src, edge_dst, edge_w, cursor, eld, N_EDGES);
  bhist_kernel<<<196, 256, 0, stream>>>(deg, bh, N_NODES);
  bscan_kernel<<<1, 256, 0, stream>>>(bh, bcur);
  bscatter_kernel<<<196, 256, 0, stream>>>(deg, bcur, perm, N_NODES);

  // layer 0: x -> h_in (relu proj) -> kqv0
  fused_layer<1><<<391, 256, 0, stream>>>(x, nullptr, Wint, b_in, nullptr, hbuf,
                                          Wcat, kwmv, qbuf, N_NODES);
  edge_agg_kernel<<<2048, 256, 0, stream>>>(kwmv, qbuf, poffs, eld, perm, agg, N_NODES);
  // layer 1: agg0 -> h0 (skip-mix+relu) -> kqv1
  fused_layer<0><<<391, 256, 0, stream>>>(nullptr, agg, Waf, nullptr, skip + 0, hbuf,
                                          Wcat + 49152, kwmv, qbuf, N_NODES);
  edge_agg_kernel<<<2048, 256, 0, stream>>>(kwmv, qbuf, poffs, eld, perm, agg, N_NODES);
  // layer 2: agg1 -> h1 (skip-mix+relu) -> kqv2
  fused_layer<0><<<391, 256, 0, stream>>>(nullptr, agg, Waf + 16384, nullptr, skip + 1,
                                          hbuf, Wcat + 98304, kwmv, qbuf, N_NODES);
  edge_agg_kernel<<<2048, 256, 0, stream>>>(kwmv, qbuf, poffs, eld, perm, agg, N_NODES);
  // final: agg2 -> hfinal (skip-mix, no relu) + hrow fp16
  gemm_last<<<391, 256, 0, stream>>>(agg, Waf + 32768, skip + 2, hbuf,
                                     hfinal, hrow, N_NODES);
  // predictor (fully fused)
  pred_fused<<<1563, 256, 0, stream>>>(hrow, pos_src, pos_dst, neg_src, neg_dst,
                                       W1f, b1, W2f, b2, W3, b3, out, 2 * N_PAIRS);
}

// Round 8
// 532.580 us; speedup vs baseline: 1.7449x; 1.0113x over previous
//
#include <hip/hip_runtime.h>
#include <cstddef>

#define N_NODES 50000
#define N_EDGES 800000
#define N_PAIRS 100000

typedef float floatx4 __attribute__((ext_vector_type(4)));
typedef _Float16 half2v __attribute__((ext_vector_type(2)));
typedef _Float16 half4v __attribute__((ext_vector_type(4)));
typedef _Float16 half8v __attribute__((ext_vector_type(8)));

// intra-wave LDS fence (validated R6): per-wave LDS + in-order DS ops means
// lgkmcnt(0) + sched_barrier replaces __syncthreads (no vmcnt drain).
#define LWAIT { asm volatile("s_waitcnt lgkmcnt(0)" ::: "memory"); __builtin_amdgcn_sched_barrier(0); }

// packed MFMA A/B-fragment layout: [tile16][kchunk32][lane][8] (fp16)
__device__ inline size_t packA(int m, int k, int K) {
  return ((size_t)((m >> 4) * (K >> 5) + (k >> 5)) << 9) +
         ((((unsigned)k >> 3) & 3) << 7) + ((m & 15) << 3) + (k & 7);
}

// ---------------- weight prep (fold + transpose + pack, fp16)
__device__ inline float fold_val(int l, int r, int j, const float* Wk, const float* Wq,
                                 const float* Wv, const float* att, const float* msg,
                                 const float* pri) {
  if (j >= 128 && j < 256) return Wq[(l * 128 + r) * 128 + (j - 128)];
  int jj = j & 127, hh = jj >> 4, e = jj & 15;
  const float* W = (j < 128) ? Wk : Wv;
  const float* T = (j < 128) ? att : msg;
  float s = 0.f;
#pragma unroll
  for (int d = 0; d < 16; d++)
    s += W[(l * 128 + r) * 128 + hh * 16 + d] * T[((l * 8 + hh) * 16 + d) * 16 + e];
  if (j < 128) s *= pri[l * 8 + hh] * 0.25f;
  return s;
}

// fused: wprep (blocks [0,880)) + edge-dst histogram (blocks [880, 880+3125))
__global__ void prep_fused(const float* __restrict__ W_in, const float* __restrict__ Wk,
                           const float* __restrict__ Wq, const float* __restrict__ Wv,
                           const float* __restrict__ att, const float* __restrict__ msg,
                           const float* __restrict__ pri, const float* __restrict__ Wa,
                           const float* __restrict__ W1, const float* __restrict__ W2,
                           _Float16* Wint, _Float16* Wcat, _Float16* Waf,
                           _Float16* W1f, _Float16* W2f,
                           const int* __restrict__ dst, int* __restrict__ deg, int E) {
  if (blockIdx.x >= 880) {
    int g = (blockIdx.x - 880) * 256 + threadIdx.x;
    if (g < E) atomicAdd(&deg[dst[g]], 1);
    return;
  }
  int gid = blockIdx.x * 256 + threadIdx.x;
  float v;
  _Float16* dt;
  size_t o;
  if (gid < 16384) {
    int n = gid >> 7, k = gid & 127;
    v = W_in[k * 128 + n];
    dt = Wint; o = packA(n, k, 128);
  } else if (gid < 163840) {
    int t = gid - 16384;
    int l = t / 49152, u = t - l * 49152;
    int n = u >> 7, k = u & 127;
    v = fold_val(l, k, n, Wk, Wq, Wv, att, msg, pri);
    dt = Wcat + (size_t)l * 49152;
    o = packA(n, k, 128);
  } else if (gid < 212992) {
    int t = gid - 163840;
    int l = t / 16384, u = t & 16383;
    int n = u >> 7, k = u & 127;
    v = Wa[(size_t)l * 16384 + k * 128 + n];
    dt = Waf + (size_t)l * 16384;
    o = packA(n, k, 128);
  } else if (gid < 221184) {
    int u = gid - 212992;
    int n = u >> 7, k = u & 127;
    v = W1[k * 64 + n];
    dt = W1f; o = packA(n, k, 128);
  } else if (gid < 225280) {
    int u = gid - 221184;
    int n = u >> 6, k = u & 63;
    v = (n < 32) ? W2[k * 32 + n] : 0.f;
    dt = W2f; o = packA(n, k, 64);
  } else {
    return;
  }
  dt[o] = (_Float16)v;
}

// ---------------- CSR scan stage A (padded-8 slots) + degree-bucket histogram
__global__ void scanA_kernel(const int* __restrict__ deg, int* __restrict__ offs,
                             int* __restrict__ bsum, int* __restrict__ bh, int n) {
  __shared__ int sm[256];
  __shared__ int lh[256];
  int t = threadIdx.x;
  int i = blockIdx.x * 256 + t;
  int dv = (i < n) ? deg[i] : 0;
  int v = (i < n) ? ((dv + 7) & ~7) : 0;
  sm[t] = v;
  __syncthreads();
  for (int off = 1; off < 256; off <<= 1) {
    int u = (t >= off) ? sm[t - off] : 0;
    __syncthreads();
    sm[t] += u;
    __syncthreads();
  }
  if (i < n) offs[i] = sm[t] - v;
  if (t == 255) bsum[blockIdx.x] = sm[255];
  // bucket histogram (bhist fused)
  lh[t] = 0;
  __syncthreads();
  if (i < n) atomicAdd(&lh[min(dv, 255)], 1);
  __syncthreads();
  if (lh[t]) atomicAdd(&bh[t], lh[t]);
}

// ---------------- fused scanC + bscatter: each block redundantly recomputes
// the tiny bsum-scan (196) and bucket-scan (256) in smem; cross-block bucket
// allocation via zero-init balloc atomics (same permutation semantics).
__global__ void scanC_fused(int* __restrict__ offs, const int* __restrict__ bsum,
                            const int* __restrict__ bh, int* __restrict__ balloc,
                            const int* __restrict__ deg, int* __restrict__ cursor,
                            int* __restrict__ perm, int nb, int n) {
  __shared__ int sA[256], sB[256], bcurL[256], lh[256], lbase[256];
  int t = threadIdx.x;
  int i = blockIdx.x * 256 + t;
  // scan of bsum (inclusive) -> block offset
  int vA = (t < nb) ? bsum[t] : 0;
  sA[t] = vA;
  __syncthreads();
  for (int off = 1; off < 256; off <<= 1) {
    int u = (t >= off) ? sA[t - off] : 0;
    __syncthreads();
    sA[t] += u;
    __syncthreads();
  }
  int boffx = sA[blockIdx.x] - bsum[blockIdx.x];  // exclusive prefix
  // bucket scan (descending bucket order, exclusive)
  int vB = bh[255 - t];
  sB[t] = vB;
  __syncthreads();
  for (int off = 1; off < 256; off <<= 1) {
    int u = (t >= off) ? sB[t - off] : 0;
    __syncthreads();
    sB[t] += u;
    __syncthreads();
  }
  bcurL[255 - t] = sB[t] - vB;
  __syncthreads();
  // offs finalize + cursor init
  int o = 0, dv = 0;
  if (i < n) {
    o = offs[i] + boffx;
    offs[i] = o;
    cursor[i] = o;
    dv = deg[i];
  }
  if (blockIdx.x == nb - 1 && t == nb - 1) offs[n] = sA[nb - 1];
  // bscatter: degree-descending permutation
  lh[t] = 0;
  __syncthreads();
  int b = 0, local = 0;
  if (i < n) {
    b = min(dv, 255);
    local = atomicAdd(&lh[b], 1);
  }
  __syncthreads();
  int cnt = lh[t];
  lbase[t] = cnt ? atomicAdd(&balloc[t], cnt) : 0;
  __syncthreads();
  if (i < n) perm[bcurL[b] + lbase[b] + local] = i;
}

__global__ void scatter_kernel(const int* __restrict__ src, const int* __restrict__ dst,
                               const float* __restrict__ w, int* __restrict__ cursor,
                               int2* __restrict__ eld, int E) {
  int g = blockIdx.x * blockDim.x + threadIdx.x;
  if (g < E) {
    int d = dst[g];
    int p = atomicAdd(&cursor[d], 1);
    eld[p] = make_int2(src[g], __float_as_int(w[g]));
  }
}

// ---------------- fused layer kernel: GEMM1 (h) -> LDS fragments -> GEMM2 (kqv)
// TWO adjacent 16-row tiles per wave (shared B fragments). [R7, unchanged]
template <int FIRST>
__global__ __launch_bounds__(256) void fused_layer(
    const float* __restrict__ x, const _Float16* __restrict__ aggp,
    const _Float16* __restrict__ Wg1, const float* __restrict__ bias,
    const float* __restrict__ skipv, _Float16* __restrict__ hbuf,
    const _Float16* __restrict__ Wcat_l,
    _Float16* __restrict__ kwmv, _Float16* __restrict__ qbuf, int M) {
  int tid = threadIdx.x;
  int wave = tid >> 6, lane = tid & 63;
  int l16 = lane & 15, q = lane >> 4;
  int g = q, mloc = l16;
  int t0 = (blockIdx.x * 4 + wave) * 2;

  __shared__ _Float16 htile_s[4][2][2048];
  __shared__ float ldsT_s[4][16 * 68];
  float* myT = ldsT_s[wave];

  float alpha = 1.f, beta = 0.f;
  if (!FIRST) {
    float sv = *skipv;
    alpha = 1.f / (1.f + __expf(-sv));
    beta = 1.f - alpha;
  }

  floatx4 acc[2][8];
#pragma unroll
  for (int t = 0; t < 2; t++)
#pragma unroll
    for (int nt = 0; nt < 8; nt++) acc[t][nt] = (floatx4){0.f, 0.f, 0.f, 0.f};

#pragma unroll
  for (int kc = 0; kc < 4; kc++) {
    half8v a0, a1;
#pragma unroll
    for (int t = 0; t < 2; t++) {
      int tile = t0 + t;
      int tileC = (tile * 16 < M) ? tile : 0;
      half8v av;
      if (FIRST) {
        int row = min(tile * 16 + l16, M - 1);
        const float* p = x + (size_t)row * 128 + kc * 32 + q * 8;
        float4 u0 = *(const float4*)p, u1 = *(const float4*)(p + 4);
        float f[8] = {u0.x, u0.y, u0.z, u0.w, u1.x, u1.y, u1.z, u1.w};
#pragma unroll
        for (int i = 0; i < 8; i++) av[i] = (_Float16)f[i];
      } else {
        av = *(const half8v*)(aggp + (size_t)tileC * 2048 + (kc << 9) + lane * 8);
      }
      if (t == 0) a0 = av; else a1 = av;
    }
#pragma unroll
    for (int nt = 0; nt < 8; nt++) {
      half8v b = *(const half8v*)(Wg1 + (size_t)nt * 2048 + (kc << 9) + lane * 8);
      acc[0][nt] = __builtin_amdgcn_mfma_f32_16x16x32_f16(a0, b, acc[0][nt], 0, 0, 0);
      acc[1][nt] = __builtin_amdgcn_mfma_f32_16x16x32_f16(a1, b, acc[1][nt], 0, 0, 0);
    }
  }

#pragma unroll
  for (int t = 0; t < 2; t++) {
    int tile = t0 + t;
    bool alive = tile * 16 < M;
    int tileC = alive ? tile : 0;
#pragma unroll
    for (int p = 0; p < 2; p++) {
#pragma unroll
      for (int ntl = 0; ntl < 4; ntl++)
#pragma unroll
        for (int r = 0; r < 4; r++)
          myT[(q * 4 + r) * 68 + ntl * 16 + l16] = acc[t][p * 4 + ntl][r];
      LWAIT;
#pragma unroll
      for (int kc2 = 0; kc2 < 2; kc2++) {
        const float* rp = myT + mloc * 68 + kc2 * 32 + g * 8;
        floatx4 v0 = *(const floatx4*)rp;
        floatx4 v1 = *(const floatx4*)(rp + 4);
        float vals[8] = {v0[0], v0[1], v0[2], v0[3], v1[0], v1[1], v1[2], v1[3]};
        int col0 = p * 64 + kc2 * 32 + g * 8;
        size_t pbaseL = ((size_t)(tileC * 4 + (col0 >> 5)) << 9) + (size_t)lane * 8;
        if (FIRST) {
          float4 bb0 = *(const float4*)&bias[col0];
          float4 bb1 = *(const float4*)&bias[col0 + 4];
          float bbv[8] = {bb0.x, bb0.y, bb0.z, bb0.w, bb1.x, bb1.y, bb1.z, bb1.w};
#pragma unroll
          for (int j = 0; j < 8; j++) vals[j] = fmaxf(vals[j] + bbv[j], 0.f);
        } else {
          half8v hv = *(const half8v*)(hbuf + pbaseL);
#pragma unroll
          for (int j = 0; j < 8; j++)
            vals[j] = fmaxf(alpha * vals[j] + beta * (float)hv[j], 0.f);
        }
        half8v h8;
#pragma unroll
        for (int j = 0; j < 8; j++) h8[j] = (_Float16)vals[j];
        *(half8v*)(&htile_s[wave][t][0] + (((p * 2 + kc2) << 9) + (g << 7) + (mloc << 3))) = h8;
        if (alive) *(half8v*)(hbuf + pbaseL) = h8;
      }
      LWAIT;
    }
  }

  LWAIT;
  for (int c = 0; c < 6; c++) {
    floatx4 acc2[2][4];
#pragma unroll
    for (int t = 0; t < 2; t++)
#pragma unroll
      for (int nt = 0; nt < 4; nt++) acc2[t][nt] = (floatx4){0.f, 0.f, 0.f, 0.f};
#pragma unroll
    for (int kc = 0; kc < 4; kc++) {
      half8v af0 = *(const half8v*)(&htile_s[wave][0][0] + ((kc << 9) + lane * 8));
      half8v af1 = *(const half8v*)(&htile_s[wave][1][0] + ((kc << 9) + lane * 8));
#pragma unroll
      for (int nt = 0; nt < 4; nt++) {
        half8v b = *(const half8v*)(Wcat_l + (size_t)(c * 4 + nt) * 2048 + (kc << 9) + lane * 8);
        acc2[0][nt] = __builtin_amdgcn_mfma_f32_16x16x32_f16(af0, b, acc2[0][nt], 0, 0, 0);
        acc2[1][nt] = __builtin_amdgcn_mfma_f32_16x16x32_f16(af1, b, acc2[1][nt], 0, 0, 0);
      }
    }
#pragma unroll
    for (int t = 0; t < 2; t++) {
      int tile = t0 + t;
      bool alive = tile * 16 < M;
      int m0 = tile * 16;
#pragma unroll
      for (int ntl = 0; ntl < 4; ntl++)
#pragma unroll
        for (int r = 0; r < 4; r++)
          myT[(q * 4 + r) * 68 + ntl * 16 + l16] = acc2[t][ntl][r];
      LWAIT;
      if (alive) {
        int row = m0 + mloc;
#pragma unroll
        for (int kc2 = 0; kc2 < 2; kc2++) {
          const float* rp = myT + mloc * 68 + kc2 * 32 + g * 8;
          floatx4 v0 = *(const floatx4*)rp;
          floatx4 v1 = *(const floatx4*)(rp + 4);
          int col0 = c * 64 + kc2 * 32 + g * 8;
          int region = col0 >> 7;  // 0 kw, 1 q, 2 mv
          if (region == 1) {
            half8v h8;
#pragma unroll
            for (int j = 0; j < 4; j++) {
              h8[j] = (_Float16)v0[j];
              h8[j + 4] = (_Float16)v1[j];
            }
            *(half8v*)&qbuf[(size_t)row * 128 + (col0 - 128)] = h8;
          } else {
            int cc = col0 & 127;
            size_t base = (size_t)row * 256 + (size_t)(cc >> 2) * 8 + (region == 2 ? 4 : 0);
            half4v h0, h1;
#pragma unroll
            for (int j = 0; j < 4; j++) {
              h0[j] = (_Float16)v0[j];
              h1[j] = (_Float16)v1[j];
            }
            *(half4v*)&kwmv[base] = h0;
            *(half4v*)&kwmv[base + 8] = h1;
          }
        }
      }
      LWAIT;
    }
  }
}

// ---------------- last Wa GEMM (2 tiles/wave) [R7, unchanged]
__global__ __launch_bounds__(256) void gemm_last(
    const _Float16* __restrict__ aggp, const _Float16* __restrict__ Wg1,
    const float* __restrict__ skipv, const _Float16* __restrict__ hbuf,
    float* __restrict__ hfinal, _Float16* __restrict__ hrow, int M) {
  int tid = threadIdx.x;
  int wave = tid >> 6, lane = tid & 63;
  int l16 = lane & 15, q = lane >> 4;
  int g = q, mloc = l16;
  int t0 = (blockIdx.x * 4 + wave) * 2;

  __shared__ float ldsT_s[4][16 * 68];
  float* myT = ldsT_s[wave];

  float sv = *skipv;
  float alpha = 1.f / (1.f + __expf(-sv));
  float beta = 1.f - alpha;

  floatx4 acc[2][8];
#pragma unroll
  for (int t = 0; t < 2; t++)
#pragma unroll
    for (int nt = 0; nt < 8; nt++) acc[t][nt] = (floatx4){0.f, 0.f, 0.f, 0.f};

#pragma unroll
  for (int kc = 0; kc < 4; kc++) {
    int tC0 = (t0 * 16 < M) ? t0 : 0;
    int tC1 = ((t0 + 1) * 16 < M) ? (t0 + 1) : 0;
    half8v a0 = *(const half8v*)(aggp + (size_t)tC0 * 2048 + (kc << 9) + lane * 8);
    half8v a1 = *(const half8v*)(aggp + (size_t)tC1 * 2048 + (kc << 9) + lane * 8);
#pragma unroll
    for (int nt = 0; nt < 8; nt++) {
      half8v b = *(const half8v*)(Wg1 + (size_t)nt * 2048 + (kc << 9) + lane * 8);
      acc[0][nt] = __builtin_amdgcn_mfma_f32_16x16x32_f16(a0, b, acc[0][nt], 0, 0, 0);
      acc[1][nt] = __builtin_amdgcn_mfma_f32_16x16x32_f16(a1, b, acc[1][nt], 0, 0, 0);
    }
  }

#pragma unroll
  for (int t = 0; t < 2; t++) {
    int tile = t0 + t;
    bool alive = tile * 16 < M;
    int m0 = tile * 16;
#pragma unroll
    for (int p = 0; p < 2; p++) {
#pragma unroll
      for (int ntl = 0; ntl < 4; ntl++)
#pragma unroll
        for (int r = 0; r < 4; r++)
          myT[(q * 4 + r) * 68 + ntl * 16 + l16] = acc[t][p * 4 + ntl][r];
      LWAIT;
      if (alive) {
        int row = m0 + mloc;
#pragma unroll
        for (int kc2 = 0; kc2 < 2; kc2++) {
          const float* rp = myT + mloc * 68 + kc2 * 32 + g * 8;
          floatx4 v0 = *(const floatx4*)rp;
          floatx4 v1 = *(const floatx4*)(rp + 4);
          float vals[8] = {v0[0], v0[1], v0[2], v0[3], v1[0], v1[1], v1[2], v1[3]};
          int col0 = p * 64 + kc2 * 32 + g * 8;
          size_t pbase = ((size_t)(tile * 4 + (col0 >> 5)) << 9) + (size_t)lane * 8;
          half8v hv = *(const half8v*)(hbuf + pbase);
#pragma unroll
          for (int j = 0; j < 8; j++) vals[j] = alpha * vals[j] + beta * (float)hv[j];
          *(float4*)&hfinal[(size_t)row * 128 + col0] =
              make_float4(vals[0], vals[1], vals[2], vals[3]);
          *(float4*)&hfinal[(size_t)row * 128 + col0 + 4] =
              make_float4(vals[4], vals[5], vals[6], vals[7]);
          half8v h8;
#pragma unroll
          for (int j = 0; j < 8; j++) h8[j] = (_Float16)vals[j];
          *(half8v*)&hrow[(size_t)row * 128 + col0] = h8;
        }
      }
      LWAIT;
    }
  }
}

// ---------------- fused predictor (2 tiles/wave) [R7, unchanged]
__global__ __launch_bounds__(256) void pred_fused(
    const _Float16* __restrict__ hrow,
    const int* __restrict__ ps, const int* __restrict__ pd,
    const int* __restrict__ ns, const int* __restrict__ nd,
    const _Float16* __restrict__ W1f, const float* __restrict__ b1,
    const _Float16* __restrict__ W2f, const float* __restrict__ b2,
    const float* __restrict__ W3, const float* __restrict__ b3,
    float* __restrict__ outd, int M) {
  int tid = threadIdx.x;
  int wave = tid >> 6, lane = tid & 63;
  int l16 = lane & 15, q = lane >> 4;
  int g = q, mloc = l16;
  int t0 = (blockIdx.x * 4 + wave) * 2;

  __shared__ _Float16 t1_s[4][2][1024];
  __shared__ float ldsT_s[4][16 * 68];
  float* myT = ldsT_s[wave];

  int pa[2], pb[2];
#pragma unroll
  for (int t = 0; t < 2; t++) {
    int gr = min((t0 + t) * 16 + l16, M - 1);
    bool pos = gr < N_PAIRS;
    int idx = pos ? gr : gr - N_PAIRS;
    pa[t] = pos ? ps[idx] : ns[idx];
    pb[t] = pos ? pd[idx] : nd[idx];
  }

  floatx4 acc1[2][4];
#pragma unroll
  for (int t = 0; t < 2; t++)
#pragma unroll
    for (int nt = 0; nt < 4; nt++) acc1[t][nt] = (floatx4){0.f, 0.f, 0.f, 0.f};

#pragma unroll
  for (int kc = 0; kc < 4; kc++) {
    int kbase = kc * 32 + q * 8;
    half8v a0, a1;
#pragma unroll
    for (int t = 0; t < 2; t++) {
      half8v ha = *(const half8v*)(hrow + (size_t)pa[t] * 128 + kbase);
      half8v hb = *(const half8v*)(hrow + (size_t)pb[t] * 128 + kbase);
      half8v av = ha * hb;
      if (t == 0) a0 = av; else a1 = av;
    }
#pragma unroll
    for (int nt = 0; nt < 4; nt++) {
      half8v b = *(const half8v*)(W1f + (size_t)nt * 2048 + (kc << 9) + lane * 8);
      acc1[0][nt] = __builtin_amdgcn_mfma_f32_16x16x32_f16(a0, b, acc1[0][nt], 0, 0, 0);
      acc1[1][nt] = __builtin_amdgcn_mfma_f32_16x16x32_f16(a1, b, acc1[1][nt], 0, 0, 0);
    }
  }

#pragma unroll
  for (int t = 0; t < 2; t++) {
#pragma unroll
    for (int ntl = 0; ntl < 4; ntl++)
#pragma unroll
      for (int r = 0; r < 4; r++)
        myT[(q * 4 + r) * 68 + ntl * 16 + l16] = acc1[t][ntl][r];
    LWAIT;
#pragma unroll
    for (int kc2 = 0; kc2 < 2; kc2++) {
      const float* rp = myT + mloc * 68 + kc2 * 32 + g * 8;
      floatx4 v0 = *(const floatx4*)rp;
      floatx4 v1 = *(const floatx4*)(rp + 4);
      float vals[8] = {v0[0], v0[1], v0[2], v0[3], v1[0], v1[1], v1[2], v1[3]};
      int col0 = kc2 * 32 + g * 8;
      float4 bb0 = *(const float4*)&b1[col0];
      float4 bb1 = *(const float4*)&b1[col0 + 4];
      float bbv[8] = {bb0.x, bb0.y, bb0.z, bb0.w, bb1.x, bb1.y, bb1.z, bb1.w};
      half8v h8;
#pragma unroll
      for (int j = 0; j < 8; j++) {
        float v = vals[j] + bbv[j];
        v = v > 0.f ? v : 0.2f * v;
        h8[j] = (_Float16)v;
      }
      *(half8v*)(&t1_s[wave][t][0] + ((kc2 << 9) + (g << 7) + (mloc << 3))) = h8;
    }
    LWAIT;
  }

  floatx4 acc2[2][2];
#pragma unroll
  for (int t = 0; t < 2; t++)
#pragma unroll
    for (int nt = 0; nt < 2; nt++) acc2[t][nt] = (floatx4){0.f, 0.f, 0.f, 0.f};
#pragma unroll
  for (int kc = 0; kc < 2; kc++) {
    half8v af0 = *(const half8v*)(&t1_s[wave][0][0] + ((kc << 9) + lane * 8));
    half8v af1 = *(const half8v*)(&t1_s[wave][1][0] + ((kc << 9) + lane * 8));
#pragma unroll
    for (int nt = 0; nt < 2; nt++) {
      half8v b = *(const half8v*)(W2f + (size_t)nt * 1024 + (kc << 9) + lane * 8);
      acc2[0][nt] = __builtin_amdgcn_mfma_f32_16x16x32_f16(af0, b, acc2[0][nt], 0, 0, 0);
      acc2[1][nt] = __builtin_amdgcn_mfma_f32_16x16x32_f16(af1, b, acc2[1][nt], 0, 0, 0);
    }
  }

  float bw[2], wv[2];
#pragma unroll
  for (int nt = 0; nt < 2; nt++) {
    int col = nt * 16 + l16;
    bw[nt] = b2[col];
    wv[nt] = W3[col];
  }
  float b3v = b3[0];
#pragma unroll
  for (int t = 0; t < 2; t++) {
    int m0 = (t0 + t) * 16;
    bool alive = m0 < M;
#pragma unroll
    for (int r = 0; r < 4; r++) {
      float partial = 0.f;
#pragma unroll
      for (int nt = 0; nt < 2; nt++) {
        float v = acc2[t][nt][r] + bw[nt];
        v = v > 0.f ? v : 0.2f * v;
        partial += v * wv[nt];
      }
      partial += __shfl_xor(partial, 1);
      partial += __shfl_xor(partial, 2);
      partial += __shfl_xor(partial, 4);
      partial += __shfl_xor(partial, 8);
      int row = m0 + q * 4 + r;
      if (l16 == 0 && alive && row < M) outd[row] = partial + b3v;
    }
  }
}

// ---------------- per-destination online-softmax aggregation [R2 best, unchanged]
__global__ __launch_bounds__(256) void edge_agg_kernel(
    const _Float16* __restrict__ kwmv, const _Float16* __restrict__ qbuf,
    const int* __restrict__ poffs, const int2* __restrict__ eld,
    const int* __restrict__ perm,
    _Float16* __restrict__ agg, int n) {
  int hw = (blockIdx.x * 256 + threadIdx.x) >> 5;
  int stride = gridDim.x << 3;
  int c4 = threadIdx.x & 31;
  int ch = c4 << 2;
  for (int gw = hw; gw < n; gw += stride) {
    int node = perm[gw];
    half4v qv = *(const half4v*)&qbuf[(size_t)node * 128 + ch];
    half2v q01 = {qv[0], qv[1]}, q23 = {qv[2], qv[3]};
    float m = -1e30f, s = 0.f;
    float a0 = 0.f, a1 = 0.f, a2 = 0.f, a3 = 0.f;
    int beg = poffs[node], end = poffs[node + 1];
    if (beg < end) {
      int2 e0[8], e1[8], e2[8];
      half8v g0[8], g1[8];
#pragma unroll
      for (int i = 0; i < 8; i++) e0[i] = eld[beg + i];
#pragma unroll
      for (int i = 0; i < 8; i++)
        g0[i] = *(const half8v*)&kwmv[(size_t)max(e0[i].x, 0) * 256 + (size_t)c4 * 8];
#pragma unroll
      for (int i = 0; i < 8; i++) e1[i] = eld[beg + 8 + i];
      int j = beg;
      for (; j + 8 < end; j += 8) {
#pragma unroll
        for (int i = 0; i < 8; i++)
          g1[i] = *(const half8v*)&kwmv[(size_t)max(e1[i].x, 0) * 256 + (size_t)c4 * 8];
#pragma unroll
        for (int i = 0; i < 8; i++) e2[i] = eld[j + 16 + i];
        float p[8];
#pragma unroll
        for (int i = 0; i < 8; i++) {
          half2v k01 = {g0[i][0], g0[i][1]}, k23 = {g0[i][2], g0[i][3]};
          float d = __builtin_amdgcn_fdot2(
              k01, q01, __builtin_amdgcn_fdot2(k23, q23, 0.f, false), false);
          d += __shfl_xor(d, 1);
          d += __shfl_xor(d, 2);
          p[i] = (e0[i].x >= 0) ? d : -1e30f;
        }
        float nm = m;
#pragma unroll
        for (int i = 0; i < 8; i++) nm = fmaxf(nm, p[i]);
        float sc = __expf(m - nm);
        float t[8];
        float ssum = 0.f;
#pragma unroll
        for (int i = 0; i < 8; i++) {
          t[i] = __expf(p[i] - nm);
          ssum += t[i];
        }
        s = s * sc + ssum;
        a0 *= sc; a1 *= sc; a2 *= sc; a3 *= sc;
#pragma unroll
        for (int i = 0; i < 8; i++) {
          float w = (e0[i].x >= 0) ? __int_as_float(e0[i].y) : 0.f;
          float f = t[i] * w;
          a0 += f * (float)g0[i][4];
          a1 += f * (float)g0[i][5];
          a2 += f * (float)g0[i][6];
          a3 += f * (float)g0[i][7];
        }
        m = nm;
#pragma unroll
        for (int i = 0; i < 8; i++) {
          e0[i] = e1[i];
          e1[i] = e2[i];
          g0[i] = g1[i];
        }
      }
      {
        float p[8];
#pragma unroll
        for (int i = 0; i < 8; i++) {
          half2v k01 = {g0[i][0], g0[i][1]}, k23 = {g0[i][2], g0[i][3]};
          float d = __builtin_amdgcn_fdot2(
              k01, q01, __builtin_amdgcn_fdot2(k23, q23, 0.f, false), false);
          d += __shfl_xor(d, 1);
          d += __shfl_xor(d, 2);
          p[i] = (e0[i].x >= 0) ? d : -1e30f;
        }
        float nm = m;
#pragma unroll
        for (int i = 0; i < 8; i++) nm = fmaxf(nm, p[i]);
        float sc = __expf(m - nm);
        float t[8];
        float ssum = 0.f;
#pragma unroll
        for (int i = 0; i < 8; i++) {
          t[i] = __expf(p[i] - nm);
          ssum += t[i];
        }
        s = s * sc + ssum;
        a0 *= sc; a1 *= sc; a2 *= sc; a3 *= sc;
#pragma unroll
        for (int i = 0; i < 8; i++) {
          float w = (e0[i].x >= 0) ? __int_as_float(e0[i].y) : 0.f;
          float f = t[i] * w;
          a0 += f * (float)g0[i][4];
          a1 += f * (float)g0[i][5];
          a2 += f * (float)g0[i][6];
          a3 += f * (float)g0[i][7];
        }
      }
    }
    float inv = (s > 0.f) ? 1.f / s : 0.f;
    half4v out4;
    out4[0] = (_Float16)(a0 * inv);
    out4[1] = (_Float16)(a1 * inv);
    out4[2] = (_Float16)(a2 * inv);
    out4[3] = (_Float16)(a3 * inv);
    *(half4v*)&agg[packA(node, ch, 128)] = out4;
  }
}

extern "C" void kernel_launch(void* const* d_in, const int* in_sizes, int n_in,
                              void* d_out, int out_size, void* d_ws, size_t ws_size,
                              hipStream_t stream) {
  const float* x        = (const float*)d_in[0];
  const int*   edge_src = (const int*)d_in[1];
  const int*   edge_dst = (const int*)d_in[2];
  const float* edge_w   = (const float*)d_in[3];
  const int*   pos_src  = (const int*)d_in[4];
  const int*   pos_dst  = (const int*)d_in[5];
  const int*   neg_src  = (const int*)d_in[6];
  const int*   neg_dst  = (const int*)d_in[7];
  const float* W_in     = (const float*)d_in[8];
  const float* b_in     = (const float*)d_in[9];
  const float* Wk       = (const float*)d_in[10];
  const float* Wq       = (const float*)d_in[11];
  const float* Wv       = (const float*)d_in[12];
  const float* att_w    = (const float*)d_in[13];
  const float* msg_w    = (const float*)d_in[14];
  const float* pri      = (const float*)d_in[15];
  const float* Wa       = (const float*)d_in[16];
  const float* skip     = (const float*)d_in[17];
  const float* W1       = (const float*)d_in[18];
  const float* b1       = (const float*)d_in[19];
  const float* W2       = (const float*)d_in[20];
  const float* b2       = (const float*)d_in[21];
  const float* W3       = (const float*)d_in[22];
  const float* b3       = (const float*)d_in[23];
  float* out = (float*)d_out;

  // ---- workspace layout (bytes), ~91 MB
  char* W = (char*)d_ws;
  _Float16*  qbuf   = (_Float16*)(W + 0);          // 12,800,000
  _Float16*  kwmv   = (_Float16*)(W + 12800000);   // 25,600,000
  _Float16*  hbuf   = (_Float16*)(W + 38400000);   // 12,800,000 (packed h)
  _Float16*  agg    = (_Float16*)(W + 51200000);   // 12,800,000
  _Float16*  Wint   = (_Float16*)(W + 64000000);   // 32,768
  _Float16*  Wcat   = (_Float16*)(W + 64032768);   // 294,912
  _Float16*  Waf    = (_Float16*)(W + 64327680);   // 98,304
  _Float16*  W1f    = (_Float16*)(W + 64425984);   // 16,384
  _Float16*  W2f    = (_Float16*)(W + 64442368);   // 8,192
  int2*      eld    = (int2*)(W + 64450560);       // 12,800,000 (padded-8 edges)
  int*       deg    = (int*)(W + 77250560);        // 200,000
  int*       bh     = (int*)(W + 77450560);        // 1,024   (adjacent: one memset)
  int*       balloc = (int*)(W + 77451584);        // 1,024
  int*       poffs  = (int*)(W + 77452608);        // 200,016
  int*       cursor = (int*)(W + 77652624);        // 200,000
  int*       perm   = (int*)(W + 77852624);        // 200,000
  int*       bsum   = (int*)(W + 78052624);        // 1,024
  _Float16*  hrow   = (_Float16*)(W + 78054912);   // 12,800,000 (fp16 row-major hfinal)
  float* hfinal = out + 2 * N_PAIRS;

  // one memset covers deg + bh + balloc (adjacent)
  hipMemsetAsync(deg, 0, 202048, stream);
  // sentinel: src=-1. pad-8 worst case: E + 7*N slots = 9.2MB
  hipMemsetAsync(eld, 0xFF, 9600000, stream);

  // wprep (880 blocks) + hist (3125 blocks) fused
  prep_fused<<<4005, 256, 0, stream>>>(W_in, Wk, Wq, Wv, att_w, msg_w, pri, Wa, W1, W2,
                                       Wint, Wcat, Waf, W1f, W2f,
                                       edge_dst, deg, N_EDGES);
  scanA_kernel<<<196, 256, 0, stream>>>(deg, poffs, bsum, bh, N_NODES);
  scanC_fused<<<196, 256, 0, stream>>>(poffs, bsum, bh, balloc, deg, cursor, perm,
                                       196, N_NODES);
  scatter_kernel<<<(N_EDGES + 255) / 256, 256, 0, stream>>>(
      edge_src, edge_dst, edge_w, cursor, eld, N_EDGES);

  // layer 0: x -> h_in (relu proj) -> kqv0
  fused_layer<1><<<391, 256, 0, stream>>>(x, nullptr, Wint, b_in, nullptr, hbuf,
                                          Wcat, kwmv, qbuf, N_NODES);
  edge_agg_kernel<<<2048, 256, 0, stream>>>(kwmv, qbuf, poffs, eld, perm, agg, N_NODES);
  // layer 1: agg0 -> h0 (skip-mix+relu) -> kqv1
  fused_layer<0><<<391, 256, 0, stream>>>(nullptr, agg, Waf, nullptr, skip + 0, hbuf,
                                          Wcat + 49152, kwmv, qbuf, N_NODES);
  edge_agg_kernel<<<2048, 256, 0, stream>>>(kwmv, qbuf, poffs, eld, perm, agg, N_NODES);
  // layer 2: agg1 -> h1 (skip-mix+relu) -> kqv2
  fused_layer<0><<<391, 256, 0, stream>>>(nullptr, agg, Waf + 16384, nullptr, skip + 1,
                                          hbuf, Wcat + 98304, kwmv, qbuf, N_NODES);
  edge_agg_kernel<<<2048, 256, 0, stream>>>(kwmv, qbuf, poffs, eld, perm, agg, N_NODES);
  // final: agg2 -> hfinal (skip-mix, no relu) + hrow fp16
  gemm_last<<<391, 256, 0, stream>>>(agg, Waf + 32768, skip + 2, hbuf,
                                     hfinal, hrow, N_NODES);
  // predictor (fully fused)
  pred_fused<<<1563, 256, 0, stream>>>(hrow, pos_src, pos_dst, neg_src, neg_dst,
                                       W1f, b1, W2f, b2, W3, b3, out, 2 * N_PAIRS);
}